// Round 2
// baseline (457.292 us; speedup 1.0000x reference)
//
#include <hip/hip_runtime.h>
#include <stdint.h>

// ---------- types ----------
typedef __attribute__((ext_vector_type(8)))  short          short8;   // 8 x bf16 bits (4 VGPR)
typedef __attribute__((ext_vector_type(8)))  unsigned short u16x8;
typedef __attribute__((ext_vector_type(4)))  unsigned short u16x4;
typedef __attribute__((ext_vector_type(4)))  float          f32x4;
typedef __attribute__((ext_vector_type(16))) float          f32x16;

__device__ __forceinline__ unsigned short f2bf(float x) {
  unsigned int u = __float_as_uint(x);
  u += 0x7fffu + ((u >> 16) & 1u);           // round-to-nearest-even
  return (unsigned short)(u >> 16);
}
__device__ __forceinline__ float bf2f(unsigned short b) {
  return __uint_as_float(((unsigned int)b) << 16);
}

// MFMA via inline asm (gfx950 unified VGPR file)
__device__ __forceinline__ void mfma16(f32x4& c, short8 a, short8 b) {
  asm volatile("v_mfma_f32_16x16x32_bf16 %0, %1, %2, %0" : "+v"(c) : "v"(a), "v"(b));
}
__device__ __forceinline__ void mfma32(f32x16& c, short8 a, short8 b) {
  asm volatile("v_mfma_f32_32x32x16_bf16 %0, %1, %2, %0" : "+v"(c) : "v"(a), "v"(b));
}

// ---------- 1) split x (fp32 -> hi/lo bf16) ----------
__global__ void split_x_kernel(const float4* __restrict__ x,
                               ushort4* __restrict__ xh, ushort4* __restrict__ xl, int n4) {
  int stride = gridDim.x * blockDim.x;
  for (int i = blockIdx.x * blockDim.x + threadIdx.x; i < n4; i += stride) {
    float4 v = x[i];
    ushort4 h, l;
    h.x = f2bf(v.x); l.x = f2bf(v.x - bf2f(h.x));
    h.y = f2bf(v.y); l.y = f2bf(v.y - bf2f(h.y));
    h.z = f2bf(v.z); l.z = f2bf(v.z - bf2f(h.z));
    h.w = f2bf(v.w); l.w = f2bf(v.w - bf2f(h.w));
    xh[i] = h; xl[i] = l;
  }
}

// ---------- 2) weight transpose + split: W[k][n] fp32 -> WT[n][k] bf16 hi/lo ----------
__global__ void wsplit_kernel(const float* __restrict__ Wq, const float* __restrict__ Wk,
                              const float* __restrict__ Wv, const float* __restrict__ Wo,
                              unsigned short* qh, unsigned short* ql,
                              unsigned short* kh, unsigned short* kl,
                              unsigned short* vh, unsigned short* vl,
                              unsigned short* oh, unsigned short* ol) {
  __shared__ float tile[32][33];
  int z = blockIdx.z;
  const float* W = (z == 0) ? Wq : (z == 1) ? Wk : (z == 2) ? Wv : Wo;
  unsigned short* Oh = (z == 0) ? qh : (z == 1) ? kh : (z == 2) ? vh : oh;
  unsigned short* Ol = (z == 0) ? ql : (z == 1) ? kl : (z == 2) ? vl : ol;
  int k0 = blockIdx.y * 32, n0 = blockIdx.x * 32;
  int tx = threadIdx.x & 31, ty = threadIdx.x >> 5;  // 32 x 8
#pragma unroll
  for (int j = 0; j < 4; ++j)
    tile[ty + 8 * j][tx] = W[(size_t)(k0 + ty + 8 * j) * 1024 + n0 + tx];
  __syncthreads();
#pragma unroll
  for (int j = 0; j < 4; ++j) {
    float v = tile[tx][ty + 8 * j];
    unsigned short h = f2bf(v);
    size_t idx = (size_t)(n0 + ty + 8 * j) * 1024 + k0 + tx;
    Oh[idx] = h;
    Ol[idx] = f2bf(v - bf2f(h));
  }
}

// ---------- 3) GEMM: C[M,N] = A[M,K] * B^T[N,K] + bias ----------
// NSPLIT: 1 = hi only, 3 = hi*hi + hi*lo + lo*hi (split-bf16 ~ fp32 accuracy)
// OUTMODE: 0 = bf16, 1 = bf16 hi/lo pair, 2 = fp32
template <int NSPLIT, int OUTMODE>
__global__ __launch_bounds__(256)
void gemm_kernel(const unsigned short* __restrict__ Ah, const unsigned short* __restrict__ Al,
                 const unsigned short* __restrict__ Bh, const unsigned short* __restrict__ Bl,
                 const float* __restrict__ bias,
                 unsigned short* __restrict__ Ch, unsigned short* __restrict__ Cl,
                 float* __restrict__ Cf, int M, int N, int K) {
  constexpr int NT = (NSPLIT == 3) ? 4 : 2;
  __shared__ unsigned short smem[NT * 8192];          // tiles of 128 rows x 64 k (16KB each)
  unsigned short* sAh = smem;
  unsigned short* sBh = smem + 8192;
  unsigned short* sAl = (NSPLIT == 3) ? smem + 2 * 8192 : smem;
  unsigned short* sBl = (NSPLIT == 3) ? smem + 3 * 8192 : smem;

  int t = threadIdx.x;
  int wid = t >> 6, l = t & 63;
  int wm = wid >> 1, wn = wid & 1;                    // 2x2 waves, 64x64 each
  int bm = blockIdx.y * 128, bn = blockIdx.x * 128;

  f32x4 acc[4][4] = {};

  for (int k0 = 0; k0 < K; k0 += 64) {
    u16x8 ra_h[4], rb_h[4], ra_l[4], rb_l[4];
#pragma unroll
    for (int r = 0; r < 4; ++r) {
      int o = (r * 256 + t) << 4;                     // byte offset in 16KB tile
      int row = o >> 7;                               // 128B rows (64 bf16)
      int col = (o & 127) >> 1;                       // element col
      size_t gA = (size_t)(bm + row) * K + k0 + col;
      size_t gB = (size_t)(bn + row) * K + k0 + col;
      ra_h[r] = *(const u16x8*)(Ah + gA);
      rb_h[r] = *(const u16x8*)(Bh + gB);
      if (NSPLIT == 3) {
        ra_l[r] = *(const u16x8*)(Al + gA);
        rb_l[r] = *(const u16x8*)(Bl + gB);
      }
    }
    __syncthreads();                                  // previous compute done
#pragma unroll
    for (int r = 0; r < 4; ++r) {
      int o = (r * 256 + t) << 4;
      int row = o >> 7;
      int d = (o ^ ((row & 7) << 4)) >> 1;            // XOR swizzle (bank-conflict fix)
      *(u16x8*)(sAh + d) = ra_h[r];
      *(u16x8*)(sBh + d) = rb_h[r];
      if (NSPLIT == 3) {
        *(u16x8*)(sAl + d) = ra_l[r];
        *(u16x8*)(sBl + d) = rb_l[r];
      }
    }
    __syncthreads();
#pragma unroll
    for (int kh = 0; kh < 2; ++kh) {
      short8 afh[4], bfh[4], afl[4], bfl[4];
#pragma unroll
      for (int m = 0; m < 4; ++m) {
        int row = wm * 64 + m * 16 + (l & 15);
        int cb = (((l >> 4) * 16 + kh * 64) ^ ((row & 7) << 4)) >> 1;
        afh[m] = *(const short8*)(sAh + row * 64 + cb);
        if (NSPLIT == 3) afl[m] = *(const short8*)(sAl + row * 64 + cb);
      }
#pragma unroll
      for (int n = 0; n < 4; ++n) {
        int row = wn * 64 + n * 16 + (l & 15);
        int cb = (((l >> 4) * 16 + kh * 64) ^ ((row & 7) << 4)) >> 1;
        bfh[n] = *(const short8*)(sBh + row * 64 + cb);
        if (NSPLIT == 3) bfl[n] = *(const short8*)(sBl + row * 64 + cb);
      }
#pragma unroll
      for (int m = 0; m < 4; ++m)
#pragma unroll
        for (int n = 0; n < 4; ++n) {
          mfma16(acc[m][n], afh[m], bfh[n]);
          if (NSPLIT == 3) {
            mfma16(acc[m][n], afh[m], bfl[n]);
            mfma16(acc[m][n], afl[m], bfh[n]);
          }
        }
    }
  }
  // epilogue: C row = (l>>4)*4 + r, col = l&15 (guide-verified C/D layout)
#pragma unroll
  for (int m = 0; m < 4; ++m) {
    int grow0 = bm + wm * 64 + m * 16 + (l >> 4) * 4;
#pragma unroll
    for (int n = 0; n < 4; ++n) {
      int gcol = bn + wn * 64 + n * 16 + (l & 15);
      float bs = bias[gcol];
#pragma unroll
      for (int r = 0; r < 4; ++r) {
        float v = acc[m][n][r] + bs;
        size_t idx = (size_t)(grow0 + r) * N + gcol;
        if (OUTMODE == 2) {
          Cf[idx] = v;
        } else {
          unsigned short hv = f2bf(v);
          Ch[idx] = hv;
          if (OUTMODE == 1) Cl[idx] = f2bf(v - bf2f(hv));
        }
      }
    }
  }
}

// ---------- 4) V transpose: V[8192][1024] -> VT[1024][8192] (bf16) ----------
__global__ void vtrans_kernel(const unsigned short* __restrict__ V, unsigned short* __restrict__ VT) {
  __shared__ unsigned short tile[64][65];
  int g0 = blockIdx.x * 64, n0 = blockIdx.y * 64;
  int tx = threadIdx.x & 63, ty = threadIdx.x >> 6;   // 64 x 4
#pragma unroll
  for (int j = 0; j < 16; ++j)
    tile[ty + 4 * j][tx] = V[(size_t)(g0 + ty + 4 * j) * 1024 + n0 + tx];
  __syncthreads();
#pragma unroll
  for (int j = 0; j < 16; ++j)
    VT[(size_t)(n0 + ty + 4 * j) * 8192 + g0 + tx] = tile[tx][ty + 4 * j];
}

// ---------- 5) fused attention (flash-style, swapped QK^T, 32x32 MFMA) ----------
// P redistribution for the PV B-frag goes through a per-wave LDS transpose
// (unambiguous; replaces the permlane32_swap packing that round 1 relied on).
__global__ __launch_bounds__(256)
void attn_kernel(const unsigned short* __restrict__ Qh, const unsigned short* __restrict__ Ql,
                 const unsigned short* __restrict__ Kh, const unsigned short* __restrict__ Kl,
                 const unsigned short* __restrict__ VT, const int* __restrict__ prefix,
                 unsigned short* __restrict__ AOh, unsigned short* __restrict__ AOl) {
  const float NEG = -3.0e38f;
  const float L2E = 1.4426950408889634f;
  __shared__ unsigned short plds[4][32][40];          // [wave][q][k], stride 40 spreads banks
  int bh = blockIdx.y;
  int b = bh >> 4, h = bh & 15;
  int wid = threadIdx.x >> 6, l = threadIdx.x & 63;
  int qb = blockIdx.x * 128 + wid * 32;               // 4 waves x 32 q-rows
  int P = prefix[b];
  int lq = l & 31, g = l >> 5;
  int q = qb + lq;

  // hoist Q^T B-frags (lane = q column), hi/lo
  short8 bqh[4], bql[4];
  {
    size_t base = (size_t)(b * 1024 + q) * 1024 + h * 64 + g * 8;
#pragma unroll
    for (int c = 0; c < 4; ++c) {
      bqh[c] = *(const short8*)(Qh + base + c * 16);
      bql[c] = *(const short8*)(Ql + base + c * 16);
    }
  }

  f32x16 o0 = {}, o1 = {};                            // O^T: d rows 0..31 / 32..63, col q
  float mrun = NEG, lrun = 0.f;

  for (int kt = 0; kt < 1024; kt += 32) {
    if (qb >= P && kt + 31 < qb) continue;            // tile fully masked for whole wave

    // S^T[k][q] = sum_d K[k][d] Q[q][d]  (A = K rows, B = Q^T)
    f32x16 s = {};
    size_t kbase = (size_t)(b * 1024 + kt + lq) * 1024 + h * 64 + g * 8;
#pragma unroll
    for (int c = 0; c < 4; ++c) {
      short8 kah = *(const short8*)(Kh + kbase + c * 16);
      short8 kal = *(const short8*)(Kl + kbase + c * 16);
      mfma32(s, kah, bqh[c]);
      mfma32(s, kah, bql[c]);
      mfma32(s, kal, bqh[c]);
    }

    // mask + online softmax (q is lane-fixed; k = kt + (r&3) + 8*(r>>2) + 4*g)
    float p[16];
    float tmax = NEG;
    bool qfull = (q < P);
#pragma unroll
    for (int r = 0; r < 16; ++r) {
      int k = kt + (r & 3) + 8 * (r >> 2) + 4 * g;
      float sv = (qfull || k >= q) ? s[r] : NEG;
      p[r] = sv;
      tmax = fmaxf(tmax, sv);
    }
    tmax = fmaxf(tmax, __shfl_xor(tmax, 32));
    float mnew = fmaxf(mrun, tmax);
    float alpha = exp2f((mrun - mnew) * L2E);
    float psum = 0.f;
#pragma unroll
    for (int r = 0; r < 16; ++r) {
      float e = exp2f((p[r] - mnew) * L2E);
      p[r] = e; psum += e;
    }
    psum += __shfl_xor(psum, 32);
    lrun = lrun * alpha + psum;
    mrun = mnew;
    o0 = o0 * alpha;
    o1 = o1 * alpha;

    // P -> LDS transpose: plds[wid][q][k] ; lane holds k = (r&3)+8*(r>>2)+4*g
#pragma unroll
    for (int tt = 0; tt < 4; ++tt) {
      u16x4 w;
      w[0] = f2bf(p[4 * tt + 0]);
      w[1] = f2bf(p[4 * tt + 1]);
      w[2] = f2bf(p[4 * tt + 2]);
      w[3] = f2bf(p[4 * tt + 3]);
      *(u16x4*)&plds[wid][lq][8 * tt + 4 * g] = w;    // k = 8*tt + 4*g + {0..3}
    }
    // B-frags for PV: lane needs P^T[k][q] with k = g*8 + j (+16 for B1)
    short8 pb0 = *(const short8*)&plds[wid][lq][g * 8];
    short8 pb1 = *(const short8*)&plds[wid][lq][16 + g * 8];

    // O^T += V^T * P^T  (A = V^T rows d, contiguous from VT)
    size_t vbase = (size_t)(h * 64 + lq) * 8192 + b * 1024 + kt + g * 8;
    short8 va00 = *(const short8*)(VT + vbase);
    short8 va01 = *(const short8*)(VT + vbase + 16);
    short8 va10 = *(const short8*)(VT + vbase + (size_t)32 * 8192);
    short8 va11 = *(const short8*)(VT + vbase + (size_t)32 * 8192 + 16);
    mfma32(o0, va00, pb0);
    mfma32(o0, va01, pb1);
    mfma32(o1, va10, pb0);
    mfma32(o1, va11, pb1);
  }

  // write AO (hi/lo) in the reference's scrambled layout:
  // AO[b, h*64 + q/16, (q%16)*64 + d]
  float inv = 1.0f / lrun;
  size_t obase = (size_t)(b * 1024 + h * 64 + (q >> 4)) * 1024 + (q & 15) * 64;
#pragma unroll
  for (int r = 0; r < 16; ++r) {
    int d = (r & 3) + 8 * (r >> 2) + 4 * g;
    float v0 = o0[r] * inv;
    float v1 = o1[r] * inv;
    unsigned short h0 = f2bf(v0), h1 = f2bf(v1);
    AOh[obase + d]      = h0;  AOl[obase + d]      = f2bf(v0 - bf2f(h0));
    AOh[obase + 32 + d] = h1;  AOl[obase + 32 + d] = f2bf(v1 - bf2f(h1));
  }
}

// ---------- launch ----------
extern "C" void kernel_launch(void* const* d_in, const int* in_sizes, int n_in,
                              void* d_out, int out_size, void* d_ws, size_t ws_size,
                              hipStream_t stream) {
  (void)in_sizes; (void)n_in; (void)out_size;
  const float* x      = (const float*)d_in[0];
  const int*   prefix = (const int*)d_in[1];
  const float* Wq = (const float*)d_in[2];
  const float* bq = (const float*)d_in[3];
  const float* Wk = (const float*)d_in[4];
  const float* bk = (const float*)d_in[5];
  const float* Wv = (const float*)d_in[6];
  const float* bv = (const float*)d_in[7];
  const float* Wo = (const float*)d_in[8];
  const float* bo = (const float*)d_in[9];
  float* out = (float*)d_out;

  const size_t MBY = 1ull << 20;
  if (ws_size < 144 * MBY) return;
  char* ws = (char*)d_ws;
  unsigned short* xh  = (unsigned short*)(ws + 0 * MBY);
  unsigned short* xl  = (unsigned short*)(ws + 16 * MBY);
  unsigned short* wqh = (unsigned short*)(ws + 32 * MBY);
  unsigned short* wql = (unsigned short*)(ws + 34 * MBY);
  unsigned short* wkh = (unsigned short*)(ws + 36 * MBY);
  unsigned short* wkl = (unsigned short*)(ws + 38 * MBY);
  unsigned short* wvh = (unsigned short*)(ws + 40 * MBY);
  unsigned short* wvl = (unsigned short*)(ws + 42 * MBY);
  unsigned short* woh = (unsigned short*)(ws + 44 * MBY);
  unsigned short* wol = (unsigned short*)(ws + 46 * MBY);
  unsigned short* Qh  = (unsigned short*)(ws + 48 * MBY);
  unsigned short* Ql  = (unsigned short*)(ws + 64 * MBY);
  unsigned short* Kh  = (unsigned short*)(ws + 80 * MBY);
  unsigned short* Kl  = (unsigned short*)(ws + 96 * MBY);
  unsigned short* V   = (unsigned short*)(ws + 112 * MBY);
  unsigned short* VT  = (unsigned short*)(ws + 128 * MBY);
  unsigned short* AOh = V;    // V dead after vtrans
  unsigned short* AOl = xh;   // x splits dead after projections

  split_x_kernel<<<1024, 256, 0, stream>>>((const float4*)x, (ushort4*)xh, (ushort4*)xl,
                                           8192 * 1024 / 4);
  wsplit_kernel<<<dim3(32, 32, 4), 256, 0, stream>>>(Wq, Wk, Wv, Wo,
                                                     wqh, wql, wkh, wkl, wvh, wvl, woh, wol);
  gemm_kernel<3, 1><<<dim3(8, 64), 256, 0, stream>>>(xh, xl, wqh, wql, bq, Qh, Ql, nullptr,
                                                     8192, 1024, 1024);
  gemm_kernel<3, 1><<<dim3(8, 64), 256, 0, stream>>>(xh, xl, wkh, wkl, bk, Kh, Kl, nullptr,
                                                     8192, 1024, 1024);
  gemm_kernel<3, 0><<<dim3(8, 64), 256, 0, stream>>>(xh, xl, wvh, wvl, bv, V, nullptr,
                                                     nullptr, 8192, 1024, 1024);
  vtrans_kernel<<<dim3(128, 16), 256, 0, stream>>>(V, VT);
  attn_kernel<<<dim3(8, 128), 256, 0, stream>>>(Qh, Ql, Kh, Kl, VT, prefix, AOh, AOl);
  gemm_kernel<3, 2><<<dim3(8, 64), 256, 0, stream>>>(AOh, AOl, woh, wol, bo, nullptr,
                                                     nullptr, out, 8192, 1024, 1024);
}

// Round 3
// 419.679 us; speedup vs baseline: 1.0896x; 1.0896x over previous
//
#include <hip/hip_runtime.h>
#include <stdint.h>

// ---------- types ----------
typedef __attribute__((ext_vector_type(8)))  short          short8;   // 8 x bf16 bits (4 VGPR)
typedef __attribute__((ext_vector_type(8)))  unsigned short u16x8;
typedef __attribute__((ext_vector_type(4)))  unsigned short u16x4;
typedef __attribute__((ext_vector_type(4)))  float          f32x4;
typedef __attribute__((ext_vector_type(16))) float          f32x16;

__device__ __forceinline__ unsigned short f2bf(float x) {
  unsigned int u = __float_as_uint(x);
  u += 0x7fffu + ((u >> 16) & 1u);           // round-to-nearest-even
  return (unsigned short)(u >> 16);
}
__device__ __forceinline__ float bf2f(unsigned short b) {
  return __uint_as_float(((unsigned int)b) << 16);
}

// MFMA via inline asm (gfx950 unified VGPR file)
__device__ __forceinline__ void mfma16(f32x4& c, short8 a, short8 b) {
  asm volatile("v_mfma_f32_16x16x32_bf16 %0, %1, %2, %0" : "+v"(c) : "v"(a), "v"(b));
}
__device__ __forceinline__ void mfma32(f32x16& c, short8 a, short8 b) {
  asm volatile("v_mfma_f32_32x32x16_bf16 %0, %1, %2, %0" : "+v"(c) : "v"(a), "v"(b));
}

// ---------- 1) split x (fp32 -> hi/lo bf16) ----------
__global__ void split_x_kernel(const float4* __restrict__ x,
                               ushort4* __restrict__ xh, ushort4* __restrict__ xl, int n4) {
  int stride = gridDim.x * blockDim.x;
  for (int i = blockIdx.x * blockDim.x + threadIdx.x; i < n4; i += stride) {
    float4 v = x[i];
    ushort4 h, l;
    h.x = f2bf(v.x); l.x = f2bf(v.x - bf2f(h.x));
    h.y = f2bf(v.y); l.y = f2bf(v.y - bf2f(h.y));
    h.z = f2bf(v.z); l.z = f2bf(v.z - bf2f(h.z));
    h.w = f2bf(v.w); l.w = f2bf(v.w - bf2f(h.w));
    xh[i] = h; xl[i] = l;
  }
}

// ---------- 2) weight transpose + split: W[k][n] fp32 -> WT[n][k] bf16 hi/lo ----------
__global__ void wsplit_kernel(const float* __restrict__ Wq, const float* __restrict__ Wk,
                              const float* __restrict__ Wv, const float* __restrict__ Wo,
                              unsigned short* qh, unsigned short* ql,
                              unsigned short* kh, unsigned short* kl,
                              unsigned short* vh, unsigned short* vl,
                              unsigned short* oh, unsigned short* ol) {
  __shared__ float tile[32][33];
  int z = blockIdx.z;
  const float* W = (z == 0) ? Wq : (z == 1) ? Wk : (z == 2) ? Wv : Wo;
  unsigned short* Oh = (z == 0) ? qh : (z == 1) ? kh : (z == 2) ? vh : oh;
  unsigned short* Ol = (z == 0) ? ql : (z == 1) ? kl : (z == 2) ? vl : ol;
  int k0 = blockIdx.y * 32, n0 = blockIdx.x * 32;
  int tx = threadIdx.x & 31, ty = threadIdx.x >> 5;  // 32 x 8
#pragma unroll
  for (int j = 0; j < 4; ++j)
    tile[ty + 8 * j][tx] = W[(size_t)(k0 + ty + 8 * j) * 1024 + n0 + tx];
  __syncthreads();
#pragma unroll
  for (int j = 0; j < 4; ++j) {
    float v = tile[tx][ty + 8 * j];
    unsigned short h = f2bf(v);
    size_t idx = (size_t)(n0 + ty + 8 * j) * 1024 + k0 + tx;
    Oh[idx] = h;
    Ol[idx] = f2bf(v - bf2f(h));
  }
}

// ---------- 3) GEMM: C[M,N] = A[M,K] * B^T[N,K] + bias ----------
// NSPLIT: 1 = hi only, 3 = hi*hi + hi*lo + lo*hi (split-bf16 ~ fp32 accuracy)
// OUTMODE: 0 = bf16, 1 = bf16 hi/lo pair, 2 = fp32
template <int NSPLIT, int OUTMODE>
__global__ __launch_bounds__(256)
void gemm_kernel(const unsigned short* __restrict__ Ah, const unsigned short* __restrict__ Al,
                 const unsigned short* __restrict__ Bh, const unsigned short* __restrict__ Bl,
                 const float* __restrict__ bias,
                 unsigned short* __restrict__ Ch, unsigned short* __restrict__ Cl,
                 float* __restrict__ Cf, int M, int N, int K) {
  constexpr int NT = (NSPLIT == 3) ? 4 : 2;
  __shared__ unsigned short smem[NT * 8192];          // tiles of 128 rows x 64 k (16KB each)
  unsigned short* sAh = smem;
  unsigned short* sBh = smem + 8192;
  unsigned short* sAl = (NSPLIT == 3) ? smem + 2 * 8192 : smem;
  unsigned short* sBl = (NSPLIT == 3) ? smem + 3 * 8192 : smem;

  int t = threadIdx.x;
  int wid = t >> 6, l = t & 63;
  int wm = wid >> 1, wn = wid & 1;                    // 2x2 waves, 64x64 each
  int bm = blockIdx.y * 128, bn = blockIdx.x * 128;

  f32x4 acc[4][4] = {};

  for (int k0 = 0; k0 < K; k0 += 64) {
    u16x8 ra_h[4], rb_h[4], ra_l[4], rb_l[4];
#pragma unroll
    for (int r = 0; r < 4; ++r) {
      int o = (r * 256 + t) << 4;                     // byte offset in 16KB tile
      int row = o >> 7;                               // 128B rows (64 bf16)
      int col = (o & 127) >> 1;                       // element col
      size_t gA = (size_t)(bm + row) * K + k0 + col;
      size_t gB = (size_t)(bn + row) * K + k0 + col;
      ra_h[r] = *(const u16x8*)(Ah + gA);
      rb_h[r] = *(const u16x8*)(Bh + gB);
      if (NSPLIT == 3) {
        ra_l[r] = *(const u16x8*)(Al + gA);
        rb_l[r] = *(const u16x8*)(Bl + gB);
      }
    }
    __syncthreads();                                  // previous compute done
#pragma unroll
    for (int r = 0; r < 4; ++r) {
      int o = (r * 256 + t) << 4;
      int row = o >> 7;
      int d = (o ^ ((row & 7) << 4)) >> 1;            // XOR swizzle (bank-conflict fix)
      *(u16x8*)(sAh + d) = ra_h[r];
      *(u16x8*)(sBh + d) = rb_h[r];
      if (NSPLIT == 3) {
        *(u16x8*)(sAl + d) = ra_l[r];
        *(u16x8*)(sBl + d) = rb_l[r];
      }
    }
    __syncthreads();
#pragma unroll
    for (int kh = 0; kh < 2; ++kh) {
      short8 afh[4], bfh[4], afl[4], bfl[4];
#pragma unroll
      for (int m = 0; m < 4; ++m) {
        int row = wm * 64 + m * 16 + (l & 15);
        int cb = (((l >> 4) * 16 + kh * 64) ^ ((row & 7) << 4)) >> 1;
        afh[m] = *(const short8*)(sAh + row * 64 + cb);
        if (NSPLIT == 3) afl[m] = *(const short8*)(sAl + row * 64 + cb);
      }
#pragma unroll
      for (int n = 0; n < 4; ++n) {
        int row = wn * 64 + n * 16 + (l & 15);
        int cb = (((l >> 4) * 16 + kh * 64) ^ ((row & 7) << 4)) >> 1;
        bfh[n] = *(const short8*)(sBh + row * 64 + cb);
        if (NSPLIT == 3) bfl[n] = *(const short8*)(sBl + row * 64 + cb);
      }
#pragma unroll
      for (int m = 0; m < 4; ++m)
#pragma unroll
        for (int n = 0; n < 4; ++n) {
          mfma16(acc[m][n], afh[m], bfh[n]);
          if (NSPLIT == 3) {
            mfma16(acc[m][n], afh[m], bfl[n]);
            mfma16(acc[m][n], afl[m], bfh[n]);
          }
        }
    }
  }
  // epilogue: C row = (l>>4)*4 + r, col = l&15 (guide-verified C/D layout)
#pragma unroll
  for (int m = 0; m < 4; ++m) {
    int grow0 = bm + wm * 64 + m * 16 + (l >> 4) * 4;
#pragma unroll
    for (int n = 0; n < 4; ++n) {
      int gcol = bn + wn * 64 + n * 16 + (l & 15);
      float bs = bias[gcol];
#pragma unroll
      for (int r = 0; r < 4; ++r) {
        float v = acc[m][n][r] + bs;
        size_t idx = (size_t)(grow0 + r) * N + gcol;
        if (OUTMODE == 2) {
          Cf[idx] = v;
        } else {
          unsigned short hv = f2bf(v);
          Ch[idx] = hv;
          if (OUTMODE == 1) Cl[idx] = f2bf(v - bf2f(hv));
        }
      }
    }
  }
}

// ---------- 4) V transpose: V[8192][1024] -> VT[1024][8192] (bf16) ----------
__global__ void vtrans_kernel(const unsigned short* __restrict__ V, unsigned short* __restrict__ VT) {
  __shared__ unsigned short tile[64][65];
  int g0 = blockIdx.x * 64, n0 = blockIdx.y * 64;
  int tx = threadIdx.x & 63, ty = threadIdx.x >> 6;   // 64 x 4
#pragma unroll
  for (int j = 0; j < 16; ++j)
    tile[ty + 4 * j][tx] = V[(size_t)(g0 + ty + 4 * j) * 1024 + n0 + tx];
  __syncthreads();
#pragma unroll
  for (int j = 0; j < 16; ++j)
    VT[(size_t)(n0 + ty + 4 * j) * 8192 + g0 + tx] = tile[tx][ty + 4 * j];
}

// ---------- 5) fused attention (flash-style, swapped QK^T, 32x32 MFMA) ----------
// grid = (bh=128, qblock=8): linear id % 8 == bh % 8 -> all q-blocks of one
// (b,h) land on the SAME XCD; K/V (~640KB/bh) stays in that XCD's 4MB L2.
// Register double-buffered K/V prefetch; defer-max rescale; cvt_pk P->bf16.
__global__ __launch_bounds__(256)
void attn_kernel(const unsigned short* __restrict__ Qh, const unsigned short* __restrict__ Ql,
                 const unsigned short* __restrict__ Kh, const unsigned short* __restrict__ Kl,
                 const unsigned short* __restrict__ VT, const int* __restrict__ prefix,
                 unsigned short* __restrict__ AOh, unsigned short* __restrict__ AOl) {
  const float NEG = -3.0e38f;
  const float L2E = 1.4426950408889634f;
  __shared__ unsigned short plds[4][32][40];          // [wave][q][k], stride 40 spreads banks
  int bh = blockIdx.x;
  int b = bh >> 4, h = bh & 15;
  int wid = threadIdx.x >> 6, l = threadIdx.x & 63;
  int qb = blockIdx.y * 128 + wid * 32;               // 4 waves x 32 q-rows
  int P = prefix[b];
  int lq = l & 31, g = l >> 5;
  int q = qb + lq;

  // hoist Q^T B-frags (lane = q column), hi/lo
  short8 bqh[4], bql[4];
  {
    size_t base = (size_t)(b * 1024 + q) * 1024 + h * 64 + g * 8;
#pragma unroll
    for (int c = 0; c < 4; ++c) {
      bqh[c] = *(const short8*)(Qh + base + c * 16);
      bql[c] = *(const short8*)(Ql + base + c * 16);
    }
  }

  const unsigned short* KhB = Kh + (size_t)b * 1024 * 1024 + h * 64 + g * 8;
  const unsigned short* KlB = Kl + (size_t)b * 1024 * 1024 + h * 64 + g * 8;
  const unsigned short* VTB = VT + (size_t)(h * 64 + lq) * 8192 + b * 1024 + g * 8;

  f32x16 o0 = {}, o1 = {};                            // O^T: d rows 0..31 / 32..63, col q
  float mrun = NEG, lrun = 0.f;
  bool qfull = (q < P);

  // first non-fully-masked tile for this wave
  int kt0 = (qb >= P) ? qb : 0;

  auto loadK = [&](int kt, short8* kd, short8* ld) {
    size_t rb = (size_t)(kt + lq) * 1024;
#pragma unroll
    for (int c = 0; c < 4; ++c) {
      kd[c] = *(const short8*)(KhB + rb + c * 16);
      ld[c] = *(const short8*)(KlB + rb + c * 16);
    }
  };
  auto loadV = [&](int kt, short8* vd) {
    vd[0] = *(const short8*)(VTB + kt);
    vd[1] = *(const short8*)(VTB + kt + 16);
    vd[2] = *(const short8*)(VTB + kt + (size_t)32 * 8192);
    vd[3] = *(const short8*)(VTB + kt + (size_t)32 * 8192 + 16);
  };

  auto body = [&](int kt, const short8* kh_, const short8* kl_, const short8* v_) {
    // S^T[k][q] = sum_d K[k][d] Q[q][d]
    f32x16 s = {};
    __builtin_amdgcn_s_setprio(1);
#pragma unroll
    for (int c = 0; c < 4; ++c) {
      mfma32(s, kh_[c], bqh[c]);
      mfma32(s, kh_[c], bql[c]);
      mfma32(s, kl_[c], bqh[c]);
    }
    __builtin_amdgcn_s_setprio(0);

    // mask + online softmax (q lane-fixed; k = kt + (r&3) + 8*(r>>2) + 4*g)
    float p[16];
    float tmax = NEG;
#pragma unroll
    for (int r = 0; r < 16; ++r) {
      int k = kt + (r & 3) + 8 * (r >> 2) + 4 * g;
      float sv = (qfull || k >= q) ? s[r] : NEG;
      p[r] = sv;
      tmax = fmaxf(tmax, sv);
    }
    tmax = fmaxf(tmax, __shfl_xor(tmax, 32));
    // defer-max (T13): only rescale when some lane's max grew past THR=8
    if (!__all(tmax - mrun <= 8.0f)) {
      float mnew = fmaxf(mrun, tmax);
      float al = exp2f((mrun - mnew) * L2E);          // NEG-NEG=0 -> al=1 (safe)
      lrun *= al; o0 *= al; o1 *= al;
      mrun = mnew;
    }
    float psum = 0.f;
#pragma unroll
    for (int r = 0; r < 16; ++r) {
      float e = exp2f((p[r] - mrun) * L2E);           // subtract first: NEG-NEG=0
      p[r] = e; psum += e;
    }
    psum += __shfl_xor(psum, 32);
    lrun += psum;

    // P -> LDS transpose via cvt_pk (pairs of adjacent k)
#pragma unroll
    for (int tt = 0; tt < 4; ++tt) {
      unsigned int u0, u1;
      asm("v_cvt_pk_bf16_f32 %0, %1, %2" : "=v"(u0) : "v"(p[4 * tt]),     "v"(p[4 * tt + 1]));
      asm("v_cvt_pk_bf16_f32 %0, %1, %2" : "=v"(u1) : "v"(p[4 * tt + 2]), "v"(p[4 * tt + 3]));
      uint2 w; w.x = u0; w.y = u1;
      *(uint2*)&plds[wid][lq][8 * tt + 4 * g] = w;    // k = 8*tt + 4*g + {0..3}
    }
    short8 pb0 = *(const short8*)&plds[wid][lq][g * 8];
    short8 pb1 = *(const short8*)&plds[wid][lq][16 + g * 8];

    // O^T += V^T * P^T
    __builtin_amdgcn_s_setprio(1);
    mfma32(o0, v_[0], pb0);
    mfma32(o0, v_[1], pb1);
    mfma32(o1, v_[2], pb0);
    mfma32(o1, v_[3], pb1);
    __builtin_amdgcn_s_setprio(0);
  };

  // software pipeline: ping-pong K/V register buffers (static indexing)
  short8 kA[8], kB[8], vA[4], vB[4];
  loadK(kt0, kA, kA + 4);
  loadV(kt0, vA);
  int kt = kt0;
  while (true) {
    {
      int ktn = kt + 32;
      int ktp = (ktn < 1024) ? ktn : kt;
      loadK(ktp, kB, kB + 4);
      loadV(ktp, vB);
      body(kt, kA, kA + 4, vA);
      if (ktn >= 1024) break;
      kt = ktn;
    }
    {
      int ktn = kt + 32;
      int ktp = (ktn < 1024) ? ktn : kt;
      loadK(ktp, kA, kA + 4);
      loadV(ktp, vA);
      body(kt, kB, kB + 4, vB);
      if (ktn >= 1024) break;
      kt = ktn;
    }
  }

  // write AO (hi/lo) in the reference's scrambled layout:
  // AO[b, h*64 + q/16, (q%16)*64 + d]
  float inv = 1.0f / lrun;
  size_t obase = (size_t)(b * 1024 + h * 64 + (q >> 4)) * 1024 + (q & 15) * 64;
#pragma unroll
  for (int r = 0; r < 16; ++r) {
    int d = (r & 3) + 8 * (r >> 2) + 4 * g;
    float v0 = o0[r] * inv;
    float v1 = o1[r] * inv;
    unsigned short h0 = f2bf(v0), h1 = f2bf(v1);
    AOh[obase + d]      = h0;  AOl[obase + d]      = f2bf(v0 - bf2f(h0));
    AOh[obase + 32 + d] = h1;  AOl[obase + 32 + d] = f2bf(v1 - bf2f(h1));
  }
}

// ---------- launch ----------
extern "C" void kernel_launch(void* const* d_in, const int* in_sizes, int n_in,
                              void* d_out, int out_size, void* d_ws, size_t ws_size,
                              hipStream_t stream) {
  (void)in_sizes; (void)n_in; (void)out_size;
  const float* x      = (const float*)d_in[0];
  const int*   prefix = (const int*)d_in[1];
  const float* Wq = (const float*)d_in[2];
  const float* bq = (const float*)d_in[3];
  const float* Wk = (const float*)d_in[4];
  const float* bk = (const float*)d_in[5];
  const float* Wv = (const float*)d_in[6];
  const float* bv = (const float*)d_in[7];
  const float* Wo = (const float*)d_in[8];
  const float* bo = (const float*)d_in[9];
  float* out = (float*)d_out;

  const size_t MBY = 1ull << 20;
  if (ws_size < 144 * MBY) return;
  char* ws = (char*)d_ws;
  unsigned short* xh  = (unsigned short*)(ws + 0 * MBY);
  unsigned short* xl  = (unsigned short*)(ws + 16 * MBY);
  unsigned short* wqh = (unsigned short*)(ws + 32 * MBY);
  unsigned short* wql = (unsigned short*)(ws + 34 * MBY);
  unsigned short* wkh = (unsigned short*)(ws + 36 * MBY);
  unsigned short* wkl = (unsigned short*)(ws + 38 * MBY);
  unsigned short* wvh = (unsigned short*)(ws + 40 * MBY);
  unsigned short* wvl = (unsigned short*)(ws + 42 * MBY);
  unsigned short* woh = (unsigned short*)(ws + 44 * MBY);
  unsigned short* wol = (unsigned short*)(ws + 46 * MBY);
  unsigned short* Qh  = (unsigned short*)(ws + 48 * MBY);
  unsigned short* Ql  = (unsigned short*)(ws + 64 * MBY);
  unsigned short* Kh  = (unsigned short*)(ws + 80 * MBY);
  unsigned short* Kl  = (unsigned short*)(ws + 96 * MBY);
  unsigned short* V   = (unsigned short*)(ws + 112 * MBY);
  unsigned short* VT  = (unsigned short*)(ws + 128 * MBY);
  unsigned short* AOh = V;    // V dead after vtrans
  unsigned short* AOl = xh;   // x splits dead after projections

  split_x_kernel<<<1024, 256, 0, stream>>>((const float4*)x, (ushort4*)xh, (ushort4*)xl,
                                           8192 * 1024 / 4);
  wsplit_kernel<<<dim3(32, 32, 4), 256, 0, stream>>>(Wq, Wk, Wv, Wo,
                                                     wqh, wql, wkh, wkl, wvh, wvl, woh, wol);
  gemm_kernel<3, 1><<<dim3(8, 64), 256, 0, stream>>>(xh, xl, wqh, wql, bq, Qh, Ql, nullptr,
                                                     8192, 1024, 1024);
  gemm_kernel<3, 1><<<dim3(8, 64), 256, 0, stream>>>(xh, xl, wkh, wkl, bk, Kh, Kl, nullptr,
                                                     8192, 1024, 1024);
  gemm_kernel<3, 0><<<dim3(8, 64), 256, 0, stream>>>(xh, xl, wvh, wvl, bv, V, nullptr,
                                                     nullptr, 8192, 1024, 1024);
  vtrans_kernel<<<dim3(128, 16), 256, 0, stream>>>(V, VT);
  attn_kernel<<<dim3(128, 8), 256, 0, stream>>>(Qh, Ql, Kh, Kl, VT, prefix, AOh, AOl);
  gemm_kernel<3, 2><<<dim3(8, 64), 256, 0, stream>>>(AOh, AOl, woh, wol, bo, nullptr,
                                                     nullptr, out, 8192, 1024, 1024);
}

// Round 4
// 365.175 us; speedup vs baseline: 1.2523x; 1.1493x over previous
//
#include <hip/hip_runtime.h>
#include <stdint.h>

// ---------- types ----------
typedef __attribute__((ext_vector_type(8)))  short          short8;   // 8 x bf16 bits (4 VGPR)
typedef __attribute__((ext_vector_type(8)))  unsigned short u16x8;
typedef __attribute__((ext_vector_type(4)))  unsigned short u16x4;
typedef __attribute__((ext_vector_type(4)))  float          f32x4;
typedef __attribute__((ext_vector_type(16))) float          f32x16;

__device__ __forceinline__ unsigned short f2bf(float x) {
  unsigned int u = __float_as_uint(x);
  u += 0x7fffu + ((u >> 16) & 1u);           // round-to-nearest-even
  return (unsigned short)(u >> 16);
}
__device__ __forceinline__ float bf2f(unsigned short b) {
  return __uint_as_float(((unsigned int)b) << 16);
}

// MFMA via inline asm (gfx950 unified VGPR file)
__device__ __forceinline__ void mfma16(f32x4& c, short8 a, short8 b) {
  asm volatile("v_mfma_f32_16x16x32_bf16 %0, %1, %2, %0" : "+v"(c) : "v"(a), "v"(b));
}
__device__ __forceinline__ void mfma32(f32x16& c, short8 a, short8 b) {
  asm volatile("v_mfma_f32_32x32x16_bf16 %0, %1, %2, %0" : "+v"(c) : "v"(a), "v"(b));
}

// ---------- 1) split x (fp32 -> hi/lo bf16) ----------
__global__ void split_x_kernel(const float4* __restrict__ x,
                               ushort4* __restrict__ xh, ushort4* __restrict__ xl, int n4) {
  int stride = gridDim.x * blockDim.x;
  for (int i = blockIdx.x * blockDim.x + threadIdx.x; i < n4; i += stride) {
    float4 v = x[i];
    ushort4 h, l;
    h.x = f2bf(v.x); l.x = f2bf(v.x - bf2f(h.x));
    h.y = f2bf(v.y); l.y = f2bf(v.y - bf2f(h.y));
    h.z = f2bf(v.z); l.z = f2bf(v.z - bf2f(h.z));
    h.w = f2bf(v.w); l.w = f2bf(v.w - bf2f(h.w));
    xh[i] = h; xl[i] = l;
  }
}

// ---------- 2) weight transpose + split: W[k][n] fp32 -> WT[n][k] bf16 hi/lo ----------
__global__ void wsplit_kernel(const float* __restrict__ Wq, const float* __restrict__ Wk,
                              const float* __restrict__ Wv, const float* __restrict__ Wo,
                              unsigned short* qh, unsigned short* ql,
                              unsigned short* kh, unsigned short* kl,
                              unsigned short* vh, unsigned short* vl,
                              unsigned short* oh, unsigned short* ol) {
  __shared__ float tile[32][33];
  int z = blockIdx.z;
  const float* W = (z == 0) ? Wq : (z == 1) ? Wk : (z == 2) ? Wv : Wo;
  unsigned short* Oh = (z == 0) ? qh : (z == 1) ? kh : (z == 2) ? vh : oh;
  unsigned short* Ol = (z == 0) ? ql : (z == 1) ? kl : (z == 2) ? vl : ol;
  int k0 = blockIdx.y * 32, n0 = blockIdx.x * 32;
  int tx = threadIdx.x & 31, ty = threadIdx.x >> 5;  // 32 x 8
#pragma unroll
  for (int j = 0; j < 4; ++j)
    tile[ty + 8 * j][tx] = W[(size_t)(k0 + ty + 8 * j) * 1024 + n0 + tx];
  __syncthreads();
#pragma unroll
  for (int j = 0; j < 4; ++j) {
    float v = tile[tx][ty + 8 * j];
    unsigned short h = f2bf(v);
    size_t idx = (size_t)(n0 + ty + 8 * j) * 1024 + k0 + tx;
    Oh[idx] = h;
    Ol[idx] = f2bf(v - bf2f(h));
  }
}

// ---------- 3) GEMM: C[M,N] = A[M,K] * B^T[N,K] + bias ----------
// NSPLIT: 1 = hi only, 3 = hi*hi + hi*lo + lo*hi (split-bf16 ~ fp32 accuracy)
// OUTMODE: 0 = bf16, 1 = bf16 hi/lo pair, 2 = fp32
template <int NSPLIT, int OUTMODE>
__global__ __launch_bounds__(256)
void gemm_kernel(const unsigned short* __restrict__ Ah, const unsigned short* __restrict__ Al,
                 const unsigned short* __restrict__ Bh, const unsigned short* __restrict__ Bl,
                 const float* __restrict__ bias,
                 unsigned short* __restrict__ Ch, unsigned short* __restrict__ Cl,
                 float* __restrict__ Cf, int M, int N, int K) {
  constexpr int NT = (NSPLIT == 3) ? 4 : 2;
  __shared__ unsigned short smem[NT * 8192];          // tiles of 128 rows x 64 k (16KB each)
  unsigned short* sAh = smem;
  unsigned short* sBh = smem + 8192;
  unsigned short* sAl = (NSPLIT == 3) ? smem + 2 * 8192 : smem;
  unsigned short* sBl = (NSPLIT == 3) ? smem + 3 * 8192 : smem;

  int t = threadIdx.x;
  int wid = t >> 6, l = t & 63;
  int wm = wid >> 1, wn = wid & 1;                    // 2x2 waves, 64x64 each
  int bm = blockIdx.y * 128, bn = blockIdx.x * 128;

  f32x4 acc[4][4] = {};

  for (int k0 = 0; k0 < K; k0 += 64) {
    u16x8 ra_h[4], rb_h[4], ra_l[4], rb_l[4];
#pragma unroll
    for (int r = 0; r < 4; ++r) {
      int o = (r * 256 + t) << 4;                     // byte offset in 16KB tile
      int row = o >> 7;                               // 128B rows (64 bf16)
      int col = (o & 127) >> 1;                       // element col
      size_t gA = (size_t)(bm + row) * K + k0 + col;
      size_t gB = (size_t)(bn + row) * K + k0 + col;
      ra_h[r] = *(const u16x8*)(Ah + gA);
      rb_h[r] = *(const u16x8*)(Bh + gB);
      if (NSPLIT == 3) {
        ra_l[r] = *(const u16x8*)(Al + gA);
        rb_l[r] = *(const u16x8*)(Bl + gB);
      }
    }
    __syncthreads();                                  // previous compute done
#pragma unroll
    for (int r = 0; r < 4; ++r) {
      int o = (r * 256 + t) << 4;
      int row = o >> 7;
      int d = (o ^ ((row & 7) << 4)) >> 1;            // XOR swizzle (bank-conflict fix)
      *(u16x8*)(sAh + d) = ra_h[r];
      *(u16x8*)(sBh + d) = rb_h[r];
      if (NSPLIT == 3) {
        *(u16x8*)(sAl + d) = ra_l[r];
        *(u16x8*)(sBl + d) = rb_l[r];
      }
    }
    __syncthreads();
#pragma unroll
    for (int kh = 0; kh < 2; ++kh) {
      short8 afh[4], bfh[4], afl[4], bfl[4];
#pragma unroll
      for (int m = 0; m < 4; ++m) {
        int row = wm * 64 + m * 16 + (l & 15);
        int cb = (((l >> 4) * 16 + kh * 64) ^ ((row & 7) << 4)) >> 1;
        afh[m] = *(const short8*)(sAh + row * 64 + cb);
        if (NSPLIT == 3) afl[m] = *(const short8*)(sAl + row * 64 + cb);
      }
#pragma unroll
      for (int n = 0; n < 4; ++n) {
        int row = wn * 64 + n * 16 + (l & 15);
        int cb = (((l >> 4) * 16 + kh * 64) ^ ((row & 7) << 4)) >> 1;
        bfh[n] = *(const short8*)(sBh + row * 64 + cb);
        if (NSPLIT == 3) bfl[n] = *(const short8*)(sBl + row * 64 + cb);
      }
#pragma unroll
      for (int m = 0; m < 4; ++m)
#pragma unroll
        for (int n = 0; n < 4; ++n) {
          mfma16(acc[m][n], afh[m], bfh[n]);
          if (NSPLIT == 3) {
            mfma16(acc[m][n], afh[m], bfl[n]);
            mfma16(acc[m][n], afl[m], bfh[n]);
          }
        }
    }
  }
  // epilogue: C row = (l>>4)*4 + r, col = l&15 (guide-verified C/D layout)
#pragma unroll
  for (int m = 0; m < 4; ++m) {
    int grow0 = bm + wm * 64 + m * 16 + (l >> 4) * 4;
#pragma unroll
    for (int n = 0; n < 4; ++n) {
      int gcol = bn + wn * 64 + n * 16 + (l & 15);
      float bs = bias[gcol];
#pragma unroll
      for (int r = 0; r < 4; ++r) {
        float v = acc[m][n][r] + bs;
        size_t idx = (size_t)(grow0 + r) * N + gcol;
        if (OUTMODE == 2) {
          Cf[idx] = v;
        } else {
          unsigned short hv = f2bf(v);
          Ch[idx] = hv;
          if (OUTMODE == 1) Cl[idx] = f2bf(v - bf2f(hv));
        }
      }
    }
  }
}

// ---------- 4) V transpose: V[8192][1024] -> VT[1024][8192] (bf16) ----------
__global__ void vtrans_kernel(const unsigned short* __restrict__ V, unsigned short* __restrict__ VT) {
  __shared__ unsigned short tile[64][65];
  int g0 = blockIdx.x * 64, n0 = blockIdx.y * 64;
  int tx = threadIdx.x & 63, ty = threadIdx.x >> 6;   // 64 x 4
#pragma unroll
  for (int j = 0; j < 16; ++j)
    tile[ty + 4 * j][tx] = V[(size_t)(g0 + ty + 4 * j) * 1024 + n0 + tx];
  __syncthreads();
#pragma unroll
  for (int j = 0; j < 16; ++j)
    VT[(size_t)(n0 + ty + 4 * j) * 8192 + g0 + tx] = tile[tx][ty + 4 * j];
}

// ---------- 5) fused attention: block-level LDS K/V staging, 2-phase pipeline ----------
// grid = (bh=128, qblock=8): linear id % 8 == bh % 8 -> XCD-local K/V (round-3 win).
// The 4 waves of a block share one (b,h): K/V tiles staged ONCE per block into
// double-buffered LDS (was: per-wave private loads = 4x redundant VMEM).
// T14 split: global loads for tile t+1 issue before compute(t); ds_write after barrier.
// mrun init 0.0 (not -3e38): lanes forced through fully-masked tiles get
// exp2((-3e38 - 0)*L2E) == 0 exactly; first real tile rescales normally (2^65 max, safe).
__global__ __launch_bounds__(256)
void attn_kernel(const unsigned short* __restrict__ Qh, const unsigned short* __restrict__ Ql,
                 const unsigned short* __restrict__ Kh, const unsigned short* __restrict__ Kl,
                 const unsigned short* __restrict__ VT, const int* __restrict__ prefix,
                 unsigned short* __restrict__ AOh, unsigned short* __restrict__ AOl) {
  const float NEG = -3.0e38f;
  const float L2E = 1.4426950408889634f;
  __shared__ unsigned short sKh[2][32][68];           // pad 68: 2-way-free bank spread
  __shared__ unsigned short sKl[2][32][68];
  __shared__ unsigned short sV [2][64][36];           // V^T tile [d][k], pad 36
  __shared__ unsigned short plds[4][32][40];          // per-wave P transpose

  int bh = blockIdx.x;
  int b = bh >> 4, h = bh & 15;
  int t = threadIdx.x, wid = t >> 6, l = t & 63;
  int qb0 = blockIdx.y * 128;
  int qb = qb0 + wid * 32;
  int P = prefix[b];
  int lq = l & 31, g = l >> 5;
  int q = qb + lq;
  bool qfull = (q < P);

  // hoist Q^T B-frags (lane = q column), hi/lo
  short8 bqh[4], bql[4];
  {
    size_t base = (size_t)(b * 1024 + q) * 1024 + h * 64 + g * 8;
#pragma unroll
    for (int c = 0; c < 4; ++c) {
      bqh[c] = *(const short8*)(Qh + base + c * 16);
      bql[c] = *(const short8*)(Ql + base + c * 16);
    }
  }

  const unsigned short* KhB = Kh + (size_t)b * 1024 * 1024 + h * 64;
  const unsigned short* KlB = Kl + (size_t)b * 1024 * 1024 + h * 64;
  const unsigned short* VTB = VT + (size_t)(h * 64) * 8192 + b * 1024;

  // staging coords: K tile 32x64 (8 thr/row), V^T tile 64x32 (4 thr/row)
  int srow = t >> 3, scol = (t & 7) * 8;
  int vrow = t >> 2, vcol = (t & 3) * 8;

  int kt0 = (qb0 >= P) ? qb0 : 0;                     // block-uniform start
  int ntiles = (1024 - kt0) >> 5;

  f32x16 o0 = {}, o1 = {};                            // O^T: d rows 0..31 / 32..63, col q
  float mrun = 0.0f, lrun = 0.f;

  u16x8 rkh, rkl, rv;
  // prologue: stage tile 0
  rkh = *(const u16x8*)(KhB + (size_t)(kt0 + srow) * 1024 + scol);
  rkl = *(const u16x8*)(KlB + (size_t)(kt0 + srow) * 1024 + scol);
  rv  = *(const u16x8*)(VTB + (size_t)vrow * 8192 + kt0 + vcol);
  *(u16x8*)&sKh[0][srow][scol] = rkh;
  *(u16x8*)&sKl[0][srow][scol] = rkl;
  *(u16x8*)&sV [0][vrow][vcol] = rv;
  __syncthreads();

  int cur = 0;
  for (int i = 0; i < ntiles; ++i) {
    int kt = kt0 + i * 32;
    bool more = (i + 1 < ntiles);
    if (more) {                                       // issue next tile's loads early (T14)
      int ktn = kt + 32;
      rkh = *(const u16x8*)(KhB + (size_t)(ktn + srow) * 1024 + scol);
      rkl = *(const u16x8*)(KlB + (size_t)(ktn + srow) * 1024 + scol);
      rv  = *(const u16x8*)(VTB + (size_t)vrow * 8192 + ktn + vcol);
    }

    // ---- compute on buf cur ----
    f32x16 s = {};
    __builtin_amdgcn_s_setprio(1);
#pragma unroll
    for (int c = 0; c < 4; ++c) {
      short8 ah = *(const short8*)&sKh[cur][lq][g * 8 + c * 16];
      short8 al = *(const short8*)&sKl[cur][lq][g * 8 + c * 16];
      mfma32(s, ah, bqh[c]);
      mfma32(s, ah, bql[c]);
      mfma32(s, al, bqh[c]);
    }
    __builtin_amdgcn_s_setprio(0);

    // mask (q lane-fixed; k = kt + (r&3) + 8*(r>>2) + 4*g)
    float p[16];
#pragma unroll
    for (int r = 0; r < 16; ++r) {
      int k = kt + (r & 3) + 8 * (r >> 2) + 4 * g;
      p[r] = (qfull || k >= q) ? s[r] : NEG;
    }
    // tree max
    float m01 = fmaxf(p[0], p[1]),  m23 = fmaxf(p[2], p[3]);
    float m45 = fmaxf(p[4], p[5]),  m67 = fmaxf(p[6], p[7]);
    float m89 = fmaxf(p[8], p[9]),  mab = fmaxf(p[10], p[11]);
    float mcd = fmaxf(p[12], p[13]), mef = fmaxf(p[14], p[15]);
    float tmax = fmaxf(fmaxf(fmaxf(m01, m23), fmaxf(m45, m67)),
                       fmaxf(fmaxf(m89, mab), fmaxf(mcd, mef)));
    tmax = fmaxf(tmax, __shfl_xor(tmax, 32));
    // defer-max (T13): rescale only when max grew past THR=8
    if (!__all(tmax - mrun <= 8.0f)) {
      float mnew = fmaxf(mrun, tmax);
      float al = exp2f((mrun - mnew) * L2E);
      lrun *= al; o0 *= al; o1 *= al;
      mrun = mnew;
    }
#pragma unroll
    for (int r = 0; r < 16; ++r)
      p[r] = exp2f((p[r] - mrun) * L2E);              // masked: exp2(~-3e38) == 0
    // tree sum
    float s01 = p[0] + p[1],  s23 = p[2] + p[3],  s45 = p[4] + p[5],  s67 = p[6] + p[7];
    float s89 = p[8] + p[9],  sab = p[10] + p[11], scd = p[12] + p[13], sef = p[14] + p[15];
    float psum = ((s01 + s23) + (s45 + s67)) + ((s89 + sab) + (scd + sef));
    psum += __shfl_xor(psum, 32);
    lrun += psum;

    // P -> LDS transpose via cvt_pk (pairs of adjacent k)
#pragma unroll
    for (int tt = 0; tt < 4; ++tt) {
      unsigned int u0, u1;
      asm("v_cvt_pk_bf16_f32 %0, %1, %2" : "=v"(u0) : "v"(p[4 * tt]),     "v"(p[4 * tt + 1]));
      asm("v_cvt_pk_bf16_f32 %0, %1, %2" : "=v"(u1) : "v"(p[4 * tt + 2]), "v"(p[4 * tt + 3]));
      uint2 w; w.x = u0; w.y = u1;
      *(uint2*)&plds[wid][lq][8 * tt + 4 * g] = w;    // k = 8*tt + 4*g + {0..3}
    }
    short8 pb0 = *(const short8*)&plds[wid][lq][g * 8];
    short8 pb1 = *(const short8*)&plds[wid][lq][16 + g * 8];

    // O^T += V^T * P^T (A-frags from staged sV)
    short8 va00 = *(const short8*)&sV[cur][lq][g * 8];
    short8 va01 = *(const short8*)&sV[cur][lq][16 + g * 8];
    short8 va10 = *(const short8*)&sV[cur][32 + lq][g * 8];
    short8 va11 = *(const short8*)&sV[cur][32 + lq][16 + g * 8];
    __builtin_amdgcn_s_setprio(1);
    mfma32(o0, va00, pb0);
    mfma32(o0, va01, pb1);
    mfma32(o1, va10, pb0);
    mfma32(o1, va11, pb1);
    __builtin_amdgcn_s_setprio(0);

    __syncthreads();                                  // all waves done reading buf cur
    if (more) {
      *(u16x8*)&sKh[cur ^ 1][srow][scol] = rkh;       // write-late (vmcnt by compiler)
      *(u16x8*)&sKl[cur ^ 1][srow][scol] = rkl;
      *(u16x8*)&sV [cur ^ 1][vrow][vcol] = rv;
    }
    __syncthreads();                                  // next buf ready
    cur ^= 1;
  }

  // write AO (hi/lo) in the reference's scrambled layout:
  // AO[b, h*64 + q/16, (q%16)*64 + d]
  float inv = 1.0f / lrun;
  size_t obase = (size_t)(b * 1024 + h * 64 + (q >> 4)) * 1024 + (q & 15) * 64;
#pragma unroll
  for (int r = 0; r < 16; ++r) {
    int d = (r & 3) + 8 * (r >> 2) + 4 * g;
    float v0 = o0[r] * inv;
    float v1 = o1[r] * inv;
    unsigned short h0 = f2bf(v0), h1 = f2bf(v1);
    AOh[obase + d]      = h0;  AOl[obase + d]      = f2bf(v0 - bf2f(h0));
    AOh[obase + 32 + d] = h1;  AOl[obase + 32 + d] = f2bf(v1 - bf2f(h1));
  }
}

// ---------- launch ----------
extern "C" void kernel_launch(void* const* d_in, const int* in_sizes, int n_in,
                              void* d_out, int out_size, void* d_ws, size_t ws_size,
                              hipStream_t stream) {
  (void)in_sizes; (void)n_in; (void)out_size;
  const float* x      = (const float*)d_in[0];
  const int*   prefix = (const int*)d_in[1];
  const float* Wq = (const float*)d_in[2];
  const float* bq = (const float*)d_in[3];
  const float* Wk = (const float*)d_in[4];
  const float* bk = (const float*)d_in[5];
  const float* Wv = (const float*)d_in[6];
  const float* bv = (const float*)d_in[7];
  const float* Wo = (const float*)d_in[8];
  const float* bo = (const float*)d_in[9];
  float* out = (float*)d_out;

  const size_t MBY = 1ull << 20;
  if (ws_size < 144 * MBY) return;
  char* ws = (char*)d_ws;
  unsigned short* xh  = (unsigned short*)(ws + 0 * MBY);
  unsigned short* xl  = (unsigned short*)(ws + 16 * MBY);
  unsigned short* wqh = (unsigned short*)(ws + 32 * MBY);
  unsigned short* wql = (unsigned short*)(ws + 34 * MBY);
  unsigned short* wkh = (unsigned short*)(ws + 36 * MBY);
  unsigned short* wkl = (unsigned short*)(ws + 38 * MBY);
  unsigned short* wvh = (unsigned short*)(ws + 40 * MBY);
  unsigned short* wvl = (unsigned short*)(ws + 42 * MBY);
  unsigned short* woh = (unsigned short*)(ws + 44 * MBY);
  unsigned short* wol = (unsigned short*)(ws + 46 * MBY);
  unsigned short* Qh  = (unsigned short*)(ws + 48 * MBY);
  unsigned short* Ql  = (unsigned short*)(ws + 64 * MBY);
  unsigned short* Kh  = (unsigned short*)(ws + 80 * MBY);
  unsigned short* Kl  = (unsigned short*)(ws + 96 * MBY);
  unsigned short* V   = (unsigned short*)(ws + 112 * MBY);
  unsigned short* VT  = (unsigned short*)(ws + 128 * MBY);
  unsigned short* AOh = V;    // V dead after vtrans
  unsigned short* AOl = xh;   // x splits dead after projections

  split_x_kernel<<<1024, 256, 0, stream>>>((const float4*)x, (ushort4*)xh, (ushort4*)xl,
                                           8192 * 1024 / 4);
  wsplit_kernel<<<dim3(32, 32, 4), 256, 0, stream>>>(Wq, Wk, Wv, Wo,
                                                     wqh, wql, wkh, wkl, wvh, wvl, woh, wol);
  gemm_kernel<3, 1><<<dim3(8, 64), 256, 0, stream>>>(xh, xl, wqh, wql, bq, Qh, Ql, nullptr,
                                                     8192, 1024, 1024);
  gemm_kernel<3, 1><<<dim3(8, 64), 256, 0, stream>>>(xh, xl, wkh, wkl, bk, Kh, Kl, nullptr,
                                                     8192, 1024, 1024);
  gemm_kernel<3, 0><<<dim3(8, 64), 256, 0, stream>>>(xh, xl, wvh, wvl, bv, V, nullptr,
                                                     nullptr, 8192, 1024, 1024);
  vtrans_kernel<<<dim3(128, 16), 256, 0, stream>>>(V, VT);
  attn_kernel<<<dim3(128, 8), 256, 0, stream>>>(Qh, Ql, Kh, Kl, VT, prefix, AOh, AOl);
  gemm_kernel<3, 2><<<dim3(8, 64), 256, 0, stream>>>(AOh, AOl, woh, wol, bo, nullptr,
                                                     nullptr, out, 8192, 1024, 1024);
}

// Round 5
// 295.508 us; speedup vs baseline: 1.5475x; 1.2358x over previous
//
#include <hip/hip_runtime.h>
#include <stdint.h>

// ---------- types ----------
typedef __attribute__((ext_vector_type(8)))  short          short8;   // 8 x bf16 bits (4 VGPR)
typedef __attribute__((ext_vector_type(8)))  unsigned short u16x8;
typedef __attribute__((ext_vector_type(4)))  unsigned short u16x4;
typedef __attribute__((ext_vector_type(4)))  float          f32x4;
typedef __attribute__((ext_vector_type(16))) float          f32x16;

__device__ __forceinline__ unsigned short f2bf(float x) {
  unsigned int u = __float_as_uint(x);
  u += 0x7fffu + ((u >> 16) & 1u);           // round-to-nearest-even
  return (unsigned short)(u >> 16);
}
__device__ __forceinline__ float bf2f(unsigned short b) {
  return __uint_as_float(((unsigned int)b) << 16);
}

// MFMA via inline asm (gfx950 unified VGPR file)
__device__ __forceinline__ void mfma16(f32x4& c, short8 a, short8 b) {
  asm volatile("v_mfma_f32_16x16x32_bf16 %0, %1, %2, %0" : "+v"(c) : "v"(a), "v"(b));
}
__device__ __forceinline__ void mfma32(f32x16& c, short8 a, short8 b) {
  asm volatile("v_mfma_f32_32x32x16_bf16 %0, %1, %2, %0" : "+v"(c) : "v"(a), "v"(b));
}

// ---------- 1) split x (fp32 -> hi/lo bf16) ----------
__global__ void split_x_kernel(const float4* __restrict__ x,
                               ushort4* __restrict__ xh, ushort4* __restrict__ xl, int n4) {
  int stride = gridDim.x * blockDim.x;
  for (int i = blockIdx.x * blockDim.x + threadIdx.x; i < n4; i += stride) {
    float4 v = x[i];
    ushort4 h, l;
    h.x = f2bf(v.x); l.x = f2bf(v.x - bf2f(h.x));
    h.y = f2bf(v.y); l.y = f2bf(v.y - bf2f(h.y));
    h.z = f2bf(v.z); l.z = f2bf(v.z - bf2f(h.z));
    h.w = f2bf(v.w); l.w = f2bf(v.w - bf2f(h.w));
    xh[i] = h; xl[i] = l;
  }
}

// ---------- 2) weight transpose + split: W[k][n] fp32 -> WT[n][k] bf16 hi/lo ----------
__global__ void wsplit_kernel(const float* __restrict__ Wq, const float* __restrict__ Wk,
                              const float* __restrict__ Wv, const float* __restrict__ Wo,
                              unsigned short* qh, unsigned short* ql,
                              unsigned short* kh, unsigned short* kl,
                              unsigned short* vh, unsigned short* oh) {
  __shared__ float tile[32][33];
  int z = blockIdx.z;
  const float* W = (z == 0) ? Wq : (z == 1) ? Wk : (z == 2) ? Wv : Wo;
  unsigned short* Oh = (z == 0) ? qh : (z == 1) ? kh : (z == 2) ? vh : oh;
  unsigned short* Ol = (z == 0) ? ql : (z == 1) ? kl : nullptr;
  int k0 = blockIdx.y * 32, n0 = blockIdx.x * 32;
  int tx = threadIdx.x & 31, ty = threadIdx.x >> 5;  // 32 x 8
#pragma unroll
  for (int j = 0; j < 4; ++j)
    tile[ty + 8 * j][tx] = W[(size_t)(k0 + ty + 8 * j) * 1024 + n0 + tx];
  __syncthreads();
#pragma unroll
  for (int j = 0; j < 4; ++j) {
    float v = tile[tx][ty + 8 * j];
    unsigned short h = f2bf(v);
    size_t idx = (size_t)(n0 + ty + 8 * j) * 1024 + k0 + tx;
    Oh[idx] = h;
    if (Ol) Ol[idx] = f2bf(v - bf2f(h));
  }
}

// ---------- 3) GEMM: C[M,N] = A[M,K] * B^T[N,K] + bias ----------
// NSPLIT: 1 = hi only, 3 = hi*hi + hi*lo + lo*hi (split-bf16 ~ fp32 accuracy)
// OUTMODE: 0 = bf16, 1 = bf16 hi/lo pair, 2 = fp32
template <int NSPLIT, int OUTMODE>
__global__ __launch_bounds__(256)
void gemm_kernel(const unsigned short* __restrict__ Ah, const unsigned short* __restrict__ Al,
                 const unsigned short* __restrict__ Bh, const unsigned short* __restrict__ Bl,
                 const float* __restrict__ bias,
                 unsigned short* __restrict__ Ch, unsigned short* __restrict__ Cl,
                 float* __restrict__ Cf, int M, int N, int K) {
  constexpr int NT = (NSPLIT == 3) ? 4 : 2;
  __shared__ unsigned short smem[NT * 8192];          // tiles of 128 rows x 64 k (16KB each)
  unsigned short* sAh = smem;
  unsigned short* sBh = smem + 8192;
  unsigned short* sAl = (NSPLIT == 3) ? smem + 2 * 8192 : smem;
  unsigned short* sBl = (NSPLIT == 3) ? smem + 3 * 8192 : smem;

  int t = threadIdx.x;
  int wid = t >> 6, l = t & 63;
  int wm = wid >> 1, wn = wid & 1;                    // 2x2 waves, 64x64 each
  int bm = blockIdx.y * 128, bn = blockIdx.x * 128;

  f32x4 acc[4][4] = {};

  for (int k0 = 0; k0 < K; k0 += 64) {
    u16x8 ra_h[4], rb_h[4], ra_l[4], rb_l[4];
#pragma unroll
    for (int r = 0; r < 4; ++r) {
      int o = (r * 256 + t) << 4;                     // byte offset in 16KB tile
      int row = o >> 7;                               // 128B rows (64 bf16)
      int col = (o & 127) >> 1;                       // element col
      size_t gA = (size_t)(bm + row) * K + k0 + col;
      size_t gB = (size_t)(bn + row) * K + k0 + col;
      ra_h[r] = *(const u16x8*)(Ah + gA);
      rb_h[r] = *(const u16x8*)(Bh + gB);
      if (NSPLIT == 3) {
        ra_l[r] = *(const u16x8*)(Al + gA);
        rb_l[r] = *(const u16x8*)(Bl + gB);
      }
    }
    __syncthreads();                                  // previous compute done
#pragma unroll
    for (int r = 0; r < 4; ++r) {
      int o = (r * 256 + t) << 4;
      int row = o >> 7;
      int d = (o ^ ((row & 7) << 4)) >> 1;            // XOR swizzle (bank-conflict fix)
      *(u16x8*)(sAh + d) = ra_h[r];
      *(u16x8*)(sBh + d) = rb_h[r];
      if (NSPLIT == 3) {
        *(u16x8*)(sAl + d) = ra_l[r];
        *(u16x8*)(sBl + d) = rb_l[r];
      }
    }
    __syncthreads();
#pragma unroll
    for (int kh = 0; kh < 2; ++kh) {
      short8 afh[4], bfh[4], afl[4], bfl[4];
#pragma unroll
      for (int m = 0; m < 4; ++m) {
        int row = wm * 64 + m * 16 + (l & 15);
        int cb = (((l >> 4) * 16 + kh * 64) ^ ((row & 7) << 4)) >> 1;
        afh[m] = *(const short8*)(sAh + row * 64 + cb);
        if (NSPLIT == 3) afl[m] = *(const short8*)(sAl + row * 64 + cb);
      }
#pragma unroll
      for (int n = 0; n < 4; ++n) {
        int row = wn * 64 + n * 16 + (l & 15);
        int cb = (((l >> 4) * 16 + kh * 64) ^ ((row & 7) << 4)) >> 1;
        bfh[n] = *(const short8*)(sBh + row * 64 + cb);
        if (NSPLIT == 3) bfl[n] = *(const short8*)(sBl + row * 64 + cb);
      }
#pragma unroll
      for (int m = 0; m < 4; ++m)
#pragma unroll
        for (int n = 0; n < 4; ++n) {
          mfma16(acc[m][n], afh[m], bfh[n]);
          if (NSPLIT == 3) {
            mfma16(acc[m][n], afh[m], bfl[n]);
            mfma16(acc[m][n], afl[m], bfh[n]);
          }
        }
    }
  }
  // epilogue: C row = (l>>4)*4 + r, col = l&15 (guide-verified C/D layout)
#pragma unroll
  for (int m = 0; m < 4; ++m) {
    int grow0 = bm + wm * 64 + m * 16 + (l >> 4) * 4;
#pragma unroll
    for (int n = 0; n < 4; ++n) {
      int gcol = bn + wn * 64 + n * 16 + (l & 15);
      float bs = bias[gcol];
#pragma unroll
      for (int r = 0; r < 4; ++r) {
        float v = acc[m][n][r] + bs;
        size_t idx = (size_t)(grow0 + r) * N + gcol;
        if (OUTMODE == 2) {
          Cf[idx] = v;
        } else {
          unsigned short hv = f2bf(v);
          Ch[idx] = hv;
          if (OUTMODE == 1) Cl[idx] = f2bf(v - bf2f(hv));
        }
      }
    }
  }
}

// ---------- 4) V transpose: V[8192][1024] -> VT[1024][8192] (bf16) ----------
__global__ void vtrans_kernel(const unsigned short* __restrict__ V, unsigned short* __restrict__ VT) {
  __shared__ unsigned short tile[64][65];
  int g0 = blockIdx.x * 64, n0 = blockIdx.y * 64;
  int tx = threadIdx.x & 63, ty = threadIdx.x >> 6;   // 64 x 4
#pragma unroll
  for (int j = 0; j < 16; ++j)
    tile[ty + 4 * j][tx] = V[(size_t)(g0 + ty + 4 * j) * 1024 + n0 + tx];
  __syncthreads();
#pragma unroll
  for (int j = 0; j < 16; ++j)
    VT[(size_t)(n0 + ty + 4 * j) * 8192 + g0 + tx] = tile[tx][ty + 4 * j];
}

// ---------- 5) fused attention: block-level LDS K/V staging, 2-phase pipeline ----------
// grid = (bh=128, qblock=8): XCD-local K/V. Cooperative double-buffered LDS staging.
// This round: wave-uniform dead-tile skip, no-mask fast path (only the diagonal
// tile needs masking under the anti-causal mask), odd-dword LDS row strides,
// vectorized bf16-only epilogue (AO-lo dropped; out-proj error budget allows it).
__global__ __launch_bounds__(256)
void attn_kernel(const unsigned short* __restrict__ Qh, const unsigned short* __restrict__ Ql,
                 const unsigned short* __restrict__ Kh, const unsigned short* __restrict__ Kl,
                 const unsigned short* __restrict__ VT, const int* __restrict__ prefix,
                 unsigned short* __restrict__ AOh) {
  const float NEG = -3.0e38f;
  const float L2E = 1.4426950408889634f;
  __shared__ unsigned short sKh[2][32][66];           // 66 shorts = 33 dwords (odd) per row
  __shared__ unsigned short sKl[2][32][66];
  __shared__ unsigned short sV [2][64][34];           // 34 shorts = 17 dwords (odd)
  __shared__ unsigned short plds[4][32][34];          // per-wave P transpose

  int bh = blockIdx.x;
  int b = bh >> 4, h = bh & 15;
  int t = threadIdx.x, wid = t >> 6, l = t & 63;
  int qb0 = blockIdx.y * 128;
  int qb = qb0 + wid * 32;
  int P = prefix[b];
  int lq = l & 31, g = l >> 5;
  int q = qb + lq;
  bool qfull = (q < P);
  bool allfull = (P >= qb + 32);                      // wave-uniform: every row full

  // hoist Q^T B-frags (lane = q column), hi/lo
  short8 bqh[4], bql[4];
  {
    size_t base = (size_t)(b * 1024 + q) * 1024 + h * 64 + g * 8;
#pragma unroll
    for (int c = 0; c < 4; ++c) {
      bqh[c] = *(const short8*)(Qh + base + c * 16);
      bql[c] = *(const short8*)(Ql + base + c * 16);
    }
  }

  const unsigned short* KhB = Kh + (size_t)b * 1024 * 1024 + h * 64;
  const unsigned short* KlB = Kl + (size_t)b * 1024 * 1024 + h * 64;
  const unsigned short* VTB = VT + (size_t)(h * 64) * 8192 + b * 1024;

  // staging coords: K tile 32x64 (8 thr/row), V^T tile 64x32 (4 thr/row)
  int srow = t >> 3, scol = (t & 7) * 8;
  int vrow = t >> 2, vcol = (t & 3) * 8;

  int kt0 = (qb0 >= P) ? qb0 : 0;                     // block-uniform start
  int ntiles = (1024 - kt0) >> 5;

  f32x16 o0 = {}, o1 = {};                            // O^T: d rows 0..31 / 32..63, col q
  float mrun = 0.0f, lrun = 0.f;

  u16x8 rkh, rkl, rv;
  // prologue: stage tile 0
  rkh = *(const u16x8*)(KhB + (size_t)(kt0 + srow) * 1024 + scol);
  rkl = *(const u16x8*)(KlB + (size_t)(kt0 + srow) * 1024 + scol);
  rv  = *(const u16x8*)(VTB + (size_t)vrow * 8192 + kt0 + vcol);
  *(u16x8*)&sKh[0][srow][scol] = rkh;
  *(u16x8*)&sKl[0][srow][scol] = rkl;
  *(u16x8*)&sV [0][vrow][vcol] = rv;
  __syncthreads();

  int cur = 0;
  for (int i = 0; i < ntiles; ++i) {
    int kt = kt0 + i * 32;
    bool more = (i + 1 < ntiles);
    if (more) {                                       // issue next tile's loads early (T14)
      int ktn = kt + 32;
      rkh = *(const u16x8*)(KhB + (size_t)(ktn + srow) * 1024 + scol);
      rkl = *(const u16x8*)(KlB + (size_t)(ktn + srow) * 1024 + scol);
      rv  = *(const u16x8*)(VTB + (size_t)vrow * 8192 + ktn + vcol);
    }

    // wave-uniform: tile contributes nothing for this wave's q-rows
    bool wave_dead = (qb >= P) && (kt + 31 < qb);
    if (!wave_dead) {
      // ---- compute on buf cur ----
      f32x16 s = {};
      __builtin_amdgcn_s_setprio(1);
#pragma unroll
      for (int c = 0; c < 4; ++c) {
        short8 ah = *(const short8*)&sKh[cur][lq][g * 8 + c * 16];
        short8 al = *(const short8*)&sKl[cur][lq][g * 8 + c * 16];
        mfma32(s, ah, bqh[c]);
        mfma32(s, ah, bql[c]);
        mfma32(s, al, bqh[c]);
      }
      __builtin_amdgcn_s_setprio(0);

      // mask: only the diagonal tile (kt == qb, not all-full) needs per-element work
      float p[16];
      if (allfull || kt > qb) {
#pragma unroll
        for (int r = 0; r < 16; ++r) p[r] = s[r];
      } else {
#pragma unroll
        for (int r = 0; r < 16; ++r) {
          int k = kt + (r & 3) + 8 * (r >> 2) + 4 * g;
          p[r] = (qfull || k >= q) ? s[r] : NEG;
        }
      }
      // tree max
      float m01 = fmaxf(p[0], p[1]),  m23 = fmaxf(p[2], p[3]);
      float m45 = fmaxf(p[4], p[5]),  m67 = fmaxf(p[6], p[7]);
      float m89 = fmaxf(p[8], p[9]),  mab = fmaxf(p[10], p[11]);
      float mcd = fmaxf(p[12], p[13]), mef = fmaxf(p[14], p[15]);
      float tmax = fmaxf(fmaxf(fmaxf(m01, m23), fmaxf(m45, m67)),
                         fmaxf(fmaxf(m89, mab), fmaxf(mcd, mef)));
      tmax = fmaxf(tmax, __shfl_xor(tmax, 32));
      // defer-max (T13): rescale only when max grew past THR=8
      if (!__all(tmax - mrun <= 8.0f)) {
        float mnew = fmaxf(mrun, tmax);
        float al = exp2f((mrun - mnew) * L2E);
        lrun *= al; o0 *= al; o1 *= al;
        mrun = mnew;
      }
#pragma unroll
      for (int r = 0; r < 16; ++r)
        p[r] = exp2f((p[r] - mrun) * L2E);            // masked: exp2(~-3e38) == 0
      // tree sum
      float s01 = p[0] + p[1],  s23 = p[2] + p[3],  s45 = p[4] + p[5],  s67 = p[6] + p[7];
      float s89 = p[8] + p[9],  sab = p[10] + p[11], scd = p[12] + p[13], sef = p[14] + p[15];
      float psum = ((s01 + s23) + (s45 + s67)) + ((s89 + sab) + (scd + sef));
      psum += __shfl_xor(psum, 32);
      lrun += psum;

      // P -> LDS transpose via cvt_pk (pairs of adjacent k)
#pragma unroll
      for (int tt = 0; tt < 4; ++tt) {
        unsigned int u0, u1;
        asm("v_cvt_pk_bf16_f32 %0, %1, %2" : "=v"(u0) : "v"(p[4 * tt]),     "v"(p[4 * tt + 1]));
        asm("v_cvt_pk_bf16_f32 %0, %1, %2" : "=v"(u1) : "v"(p[4 * tt + 2]), "v"(p[4 * tt + 3]));
        uint2 w; w.x = u0; w.y = u1;
        *(uint2*)&plds[wid][lq][8 * tt + 4 * g] = w;  // k = 8*tt + 4*g + {0..3}
      }
      short8 pb0 = *(const short8*)&plds[wid][lq][g * 8];
      short8 pb1 = *(const short8*)&plds[wid][lq][16 + g * 8];

      // O^T += V^T * P^T (A-frags from staged sV)
      short8 va00 = *(const short8*)&sV[cur][lq][g * 8];
      short8 va01 = *(const short8*)&sV[cur][lq][16 + g * 8];
      short8 va10 = *(const short8*)&sV[cur][32 + lq][g * 8];
      short8 va11 = *(const short8*)&sV[cur][32 + lq][16 + g * 8];
      __builtin_amdgcn_s_setprio(1);
      mfma32(o0, va00, pb0);
      mfma32(o0, va01, pb1);
      mfma32(o1, va10, pb0);
      mfma32(o1, va11, pb1);
      __builtin_amdgcn_s_setprio(0);
    }

    __syncthreads();                                  // all waves done reading buf cur
    if (more) {
      *(u16x8*)&sKh[cur ^ 1][srow][scol] = rkh;       // write-late
      *(u16x8*)&sKl[cur ^ 1][srow][scol] = rkl;
      *(u16x8*)&sV [cur ^ 1][vrow][vcol] = rv;
    }
    __syncthreads();                                  // next buf ready
    cur ^= 1;
  }

  // write AO (bf16) in the reference's scrambled layout:
  // AO[b, h*64 + q/16, (q%16)*64 + d]; d = (r&3) + 8*(r>>2) + 4*g -> vectorized per quad
  float inv = 1.0f / lrun;
  size_t obase = (size_t)(b * 1024 + h * 64 + (q >> 4)) * 1024 + (q & 15) * 64;
#pragma unroll
  for (int tt = 0; tt < 4; ++tt) {
    u16x4 w0, w1;
#pragma unroll
    for (int j = 0; j < 4; ++j) {
      w0[j] = f2bf(o0[4 * tt + j] * inv);
      w1[j] = f2bf(o1[4 * tt + j] * inv);
    }
    *(u16x4*)(AOh + obase + 8 * tt + 4 * g)      = w0;
    *(u16x4*)(AOh + obase + 32 + 8 * tt + 4 * g) = w1;
  }
}

// ---------- launch ----------
extern "C" void kernel_launch(void* const* d_in, const int* in_sizes, int n_in,
                              void* d_out, int out_size, void* d_ws, size_t ws_size,
                              hipStream_t stream) {
  (void)in_sizes; (void)n_in; (void)out_size;
  const float* x      = (const float*)d_in[0];
  const int*   prefix = (const int*)d_in[1];
  const float* Wq = (const float*)d_in[2];
  const float* bq = (const float*)d_in[3];
  const float* Wk = (const float*)d_in[4];
  const float* bk = (const float*)d_in[5];
  const float* Wv = (const float*)d_in[6];
  const float* bv = (const float*)d_in[7];
  const float* Wo = (const float*)d_in[8];
  const float* bo = (const float*)d_in[9];
  float* out = (float*)d_out;

  const size_t MBY = 1ull << 20;
  if (ws_size < 144 * MBY) return;
  char* ws = (char*)d_ws;
  unsigned short* xh  = (unsigned short*)(ws + 0 * MBY);
  unsigned short* xl  = (unsigned short*)(ws + 16 * MBY);
  unsigned short* wqh = (unsigned short*)(ws + 32 * MBY);
  unsigned short* wql = (unsigned short*)(ws + 34 * MBY);
  unsigned short* wkh = (unsigned short*)(ws + 36 * MBY);
  unsigned short* wkl = (unsigned short*)(ws + 38 * MBY);
  unsigned short* wvh = (unsigned short*)(ws + 40 * MBY);
  unsigned short* woh = (unsigned short*)(ws + 44 * MBY);
  unsigned short* Qh  = (unsigned short*)(ws + 48 * MBY);
  unsigned short* Ql  = (unsigned short*)(ws + 64 * MBY);
  unsigned short* Kh  = (unsigned short*)(ws + 80 * MBY);
  unsigned short* Kl  = (unsigned short*)(ws + 96 * MBY);
  unsigned short* V   = (unsigned short*)(ws + 112 * MBY);
  unsigned short* VT  = (unsigned short*)(ws + 128 * MBY);
  unsigned short* AOh = V;    // V dead after vtrans
  unsigned short* AOl = xh;   // (unused this round)
  (void)AOl;

  split_x_kernel<<<1024, 256, 0, stream>>>((const float4*)x, (ushort4*)xh, (ushort4*)xl,
                                           8192 * 1024 / 4);
  wsplit_kernel<<<dim3(32, 32, 4), 256, 0, stream>>>(Wq, Wk, Wv, Wo,
                                                     wqh, wql, wkh, wkl, wvh, woh);
  gemm_kernel<3, 1><<<dim3(8, 64), 256, 0, stream>>>(xh, xl, wqh, wql, bq, Qh, Ql, nullptr,
                                                     8192, 1024, 1024);
  gemm_kernel<3, 1><<<dim3(8, 64), 256, 0, stream>>>(xh, xl, wkh, wkl, bk, Kh, Kl, nullptr,
                                                     8192, 1024, 1024);
  gemm_kernel<1, 0><<<dim3(8, 64), 256, 0, stream>>>(xh, nullptr, wvh, nullptr, bv, V, nullptr,
                                                     nullptr, 8192, 1024, 1024);
  vtrans_kernel<<<dim3(128, 16), 256, 0, stream>>>(V, VT);
  attn_kernel<<<dim3(128, 8), 256, 0, stream>>>(Qh, Ql, Kh, Kl, VT, prefix, AOh);
  gemm_kernel<1, 2><<<dim3(8, 64), 256, 0, stream>>>(AOh, nullptr, woh, nullptr, bo, nullptr,
                                                     nullptr, out, 8192, 1024, 1024);
}

// Round 6
// 280.951 us; speedup vs baseline: 1.6277x; 1.0518x over previous
//
#include <hip/hip_runtime.h>
#include <stdint.h>

// ---------- types ----------
typedef __attribute__((ext_vector_type(8)))  short          short8;   // 8 x bf16 bits (4 VGPR)
typedef __attribute__((ext_vector_type(8)))  unsigned short u16x8;
typedef __attribute__((ext_vector_type(4)))  unsigned short u16x4;
typedef __attribute__((ext_vector_type(4)))  float          f32x4;
typedef __attribute__((ext_vector_type(16))) float          f32x16;

__device__ __forceinline__ unsigned short f2bf(float x) {
  unsigned int u = __float_as_uint(x);
  u += 0x7fffu + ((u >> 16) & 1u);           // round-to-nearest-even
  return (unsigned short)(u >> 16);
}
__device__ __forceinline__ float bf2f(unsigned short b) {
  return __uint_as_float(((unsigned int)b) << 16);
}

// MFMA via inline asm (gfx950 unified VGPR file)
__device__ __forceinline__ void mfma16(f32x4& c, short8 a, short8 b) {
  asm volatile("v_mfma_f32_16x16x32_bf16 %0, %1, %2, %0" : "+v"(c) : "v"(a), "v"(b));
}
__device__ __forceinline__ void mfma32(f32x16& c, short8 a, short8 b) {
  asm volatile("v_mfma_f32_32x32x16_bf16 %0, %1, %2, %0" : "+v"(c) : "v"(a), "v"(b));
}

// ---------- 1) split x (fp32 -> hi/lo bf16) ----------
__global__ void split_x_kernel(const float4* __restrict__ x,
                               ushort4* __restrict__ xh, ushort4* __restrict__ xl, int n4) {
  int stride = gridDim.x * blockDim.x;
  for (int i = blockIdx.x * blockDim.x + threadIdx.x; i < n4; i += stride) {
    float4 v = x[i];
    ushort4 h, l;
    h.x = f2bf(v.x); l.x = f2bf(v.x - bf2f(h.x));
    h.y = f2bf(v.y); l.y = f2bf(v.y - bf2f(h.y));
    h.z = f2bf(v.z); l.z = f2bf(v.z - bf2f(h.z));
    h.w = f2bf(v.w); l.w = f2bf(v.w - bf2f(h.w));
    xh[i] = h; xl[i] = l;
  }
}

// ---------- 2) weight transpose + split: W[k][n] fp32 -> WT[n][k] bf16 hi/lo ----------
__global__ void wsplit_kernel(const float* __restrict__ Wq, const float* __restrict__ Wk,
                              const float* __restrict__ Wv, const float* __restrict__ Wo,
                              unsigned short* qh, unsigned short* ql,
                              unsigned short* kh, unsigned short* kl,
                              unsigned short* vh, unsigned short* oh) {
  __shared__ float tile[32][33];
  int z = blockIdx.z;
  const float* W = (z == 0) ? Wq : (z == 1) ? Wk : (z == 2) ? Wv : Wo;
  unsigned short* Oh = (z == 0) ? qh : (z == 1) ? kh : (z == 2) ? vh : oh;
  unsigned short* Ol = (z == 0) ? ql : (z == 1) ? kl : nullptr;
  int k0 = blockIdx.y * 32, n0 = blockIdx.x * 32;
  int tx = threadIdx.x & 31, ty = threadIdx.x >> 5;  // 32 x 8
#pragma unroll
  for (int j = 0; j < 4; ++j)
    tile[ty + 8 * j][tx] = W[(size_t)(k0 + ty + 8 * j) * 1024 + n0 + tx];
  __syncthreads();
#pragma unroll
  for (int j = 0; j < 4; ++j) {
    float v = tile[tx][ty + 8 * j];
    unsigned short h = f2bf(v);
    size_t idx = (size_t)(n0 + ty + 8 * j) * 1024 + k0 + tx;
    Oh[idx] = h;
    if (Ol) Ol[idx] = f2bf(v - bf2f(h));
  }
}

// ---------- 3) GEMM: C[M,N] = A[M,K] * B^T[N,K] + bias ----------
// NSPLIT: 1 = hi only, 3 = hi*hi + hi*lo + lo*hi (split-bf16 ~ fp32 accuracy)
// OUTMODE: 0 = bf16, 1 = bf16 hi/lo pair, 2 = fp32
template <int NSPLIT, int OUTMODE>
__global__ __launch_bounds__(256)
void gemm_kernel(const unsigned short* __restrict__ Ah, const unsigned short* __restrict__ Al,
                 const unsigned short* __restrict__ Bh, const unsigned short* __restrict__ Bl,
                 const float* __restrict__ bias,
                 unsigned short* __restrict__ Ch, unsigned short* __restrict__ Cl,
                 float* __restrict__ Cf, int M, int N, int K) {
  constexpr int NT = (NSPLIT == 3) ? 4 : 2;
  __shared__ unsigned short smem[NT * 8192];          // tiles of 128 rows x 64 k (16KB each)
  unsigned short* sAh = smem;
  unsigned short* sBh = smem + 8192;
  unsigned short* sAl = (NSPLIT == 3) ? smem + 2 * 8192 : smem;
  unsigned short* sBl = (NSPLIT == 3) ? smem + 3 * 8192 : smem;

  int t = threadIdx.x;
  int wid = t >> 6, l = t & 63;
  int wm = wid >> 1, wn = wid & 1;                    // 2x2 waves, 64x64 each
  int bm = blockIdx.y * 128, bn = blockIdx.x * 128;

  f32x4 acc[4][4] = {};

  for (int k0 = 0; k0 < K; k0 += 64) {
    u16x8 ra_h[4], rb_h[4], ra_l[4], rb_l[4];
#pragma unroll
    for (int r = 0; r < 4; ++r) {
      int o = (r * 256 + t) << 4;                     // byte offset in 16KB tile
      int row = o >> 7;                               // 128B rows (64 bf16)
      int col = (o & 127) >> 1;                       // element col
      size_t gA = (size_t)(bm + row) * K + k0 + col;
      size_t gB = (size_t)(bn + row) * K + k0 + col;
      ra_h[r] = *(const u16x8*)(Ah + gA);
      rb_h[r] = *(const u16x8*)(Bh + gB);
      if (NSPLIT == 3) {
        ra_l[r] = *(const u16x8*)(Al + gA);
        rb_l[r] = *(const u16x8*)(Bl + gB);
      }
    }
    __syncthreads();                                  // previous compute done
#pragma unroll
    for (int r = 0; r < 4; ++r) {
      int o = (r * 256 + t) << 4;
      int row = o >> 7;
      int d = (o ^ ((row & 7) << 4)) >> 1;            // XOR swizzle (bank-conflict fix)
      *(u16x8*)(sAh + d) = ra_h[r];
      *(u16x8*)(sBh + d) = rb_h[r];
      if (NSPLIT == 3) {
        *(u16x8*)(sAl + d) = ra_l[r];
        *(u16x8*)(sBl + d) = rb_l[r];
      }
    }
    __syncthreads();
#pragma unroll
    for (int kh = 0; kh < 2; ++kh) {
      short8 afh[4], bfh[4], afl[4], bfl[4];
#pragma unroll
      for (int m = 0; m < 4; ++m) {
        int row = wm * 64 + m * 16 + (l & 15);
        int cb = (((l >> 4) * 16 + kh * 64) ^ ((row & 7) << 4)) >> 1;
        afh[m] = *(const short8*)(sAh + row * 64 + cb);
        if (NSPLIT == 3) afl[m] = *(const short8*)(sAl + row * 64 + cb);
      }
#pragma unroll
      for (int n = 0; n < 4; ++n) {
        int row = wn * 64 + n * 16 + (l & 15);
        int cb = (((l >> 4) * 16 + kh * 64) ^ ((row & 7) << 4)) >> 1;
        bfh[n] = *(const short8*)(sBh + row * 64 + cb);
        if (NSPLIT == 3) bfl[n] = *(const short8*)(sBl + row * 64 + cb);
      }
#pragma unroll
      for (int m = 0; m < 4; ++m)
#pragma unroll
        for (int n = 0; n < 4; ++n) {
          mfma16(acc[m][n], afh[m], bfh[n]);
          if (NSPLIT == 3) {
            mfma16(acc[m][n], afh[m], bfl[n]);
            mfma16(acc[m][n], afl[m], bfh[n]);
          }
        }
    }
  }
  // epilogue: C row = (l>>4)*4 + r, col = l&15 (guide-verified C/D layout)
#pragma unroll
  for (int m = 0; m < 4; ++m) {
    int grow0 = bm + wm * 64 + m * 16 + (l >> 4) * 4;
#pragma unroll
    for (int n = 0; n < 4; ++n) {
      int gcol = bn + wn * 64 + n * 16 + (l & 15);
      float bs = bias[gcol];
#pragma unroll
      for (int r = 0; r < 4; ++r) {
        float v = acc[m][n][r] + bs;
        size_t idx = (size_t)(grow0 + r) * N + gcol;
        if (OUTMODE == 2) {
          Cf[idx] = v;
        } else {
          unsigned short hv = f2bf(v);
          Ch[idx] = hv;
          if (OUTMODE == 1) Cl[idx] = f2bf(v - bf2f(hv));
        }
      }
    }
  }
}

// ---------- 4) V transpose: V[8192][1024] -> VT[1024][8192] (bf16) ----------
__global__ void vtrans_kernel(const unsigned short* __restrict__ V, unsigned short* __restrict__ VT) {
  __shared__ unsigned short tile[64][65];
  int g0 = blockIdx.x * 64, n0 = blockIdx.y * 64;
  int tx = threadIdx.x & 63, ty = threadIdx.x >> 6;   // 64 x 4
#pragma unroll
  for (int j = 0; j < 16; ++j)
    tile[ty + 4 * j][tx] = V[(size_t)(g0 + ty + 4 * j) * 1024 + n0 + tx];
  __syncthreads();
#pragma unroll
  for (int j = 0; j < 16; ++j)
    VT[(size_t)(n0 + ty + 4 * j) * 8192 + g0 + tx] = tile[tx][ty + 4 * j];
}

// ---------- 5) fused attention: block-level LDS K/V staging, 2-phase pipeline ----------
// grid = (bh=128, qblock=8): XCD-local K/V. Cooperative double-buffered LDS staging.
// This round: K-lo plane DROPPED (error budget: dropped Kl.Qh term adds ~0.006-std
// logit error -> ~0.02 output tail; measured margin 3x). Q-lo kept (register-only,
// 4 MFMA/tile, no staging). LDS 34->26KB -> 6 blocks/CU for latency hiding.
__global__ __launch_bounds__(256)
void attn_kernel(const unsigned short* __restrict__ Qh, const unsigned short* __restrict__ Ql,
                 const unsigned short* __restrict__ Kh,
                 const unsigned short* __restrict__ VT, const int* __restrict__ prefix,
                 unsigned short* __restrict__ AOh) {
  const float NEG = -3.0e38f;
  const float L2E = 1.4426950408889634f;
  __shared__ unsigned short sKh[2][32][66];           // 66 shorts = 33 dwords (odd) per row
  __shared__ unsigned short sV [2][64][34];           // 34 shorts = 17 dwords (odd)
  __shared__ unsigned short plds[4][32][34];          // per-wave P transpose

  int bh = blockIdx.x;
  int b = bh >> 4, h = bh & 15;
  int t = threadIdx.x, wid = t >> 6, l = t & 63;
  int qb0 = blockIdx.y * 128;
  int qb = qb0 + wid * 32;
  int P = prefix[b];
  int lq = l & 31, g = l >> 5;
  int q = qb + lq;
  bool qfull = (q < P);
  bool allfull = (P >= qb + 32);                      // wave-uniform: every row full

  // hoist Q^T B-frags (lane = q column), hi/lo
  short8 bqh[4], bql[4];
  {
    size_t base = (size_t)(b * 1024 + q) * 1024 + h * 64 + g * 8;
#pragma unroll
    for (int c = 0; c < 4; ++c) {
      bqh[c] = *(const short8*)(Qh + base + c * 16);
      bql[c] = *(const short8*)(Ql + base + c * 16);
    }
  }

  const unsigned short* KhB = Kh + (size_t)b * 1024 * 1024 + h * 64;
  const unsigned short* VTB = VT + (size_t)(h * 64) * 8192 + b * 1024;

  // staging coords: K tile 32x64 (8 thr/row), V^T tile 64x32 (4 thr/row)
  int srow = t >> 3, scol = (t & 7) * 8;
  int vrow = t >> 2, vcol = (t & 3) * 8;

  int kt0 = (qb0 >= P) ? qb0 : 0;                     // block-uniform start
  int ntiles = (1024 - kt0) >> 5;

  f32x16 o0 = {}, o1 = {};                            // O^T: d rows 0..31 / 32..63, col q
  float mrun = 0.0f, lrun = 0.f;

  u16x8 rkh, rv;
  // prologue: stage tile 0
  rkh = *(const u16x8*)(KhB + (size_t)(kt0 + srow) * 1024 + scol);
  rv  = *(const u16x8*)(VTB + (size_t)vrow * 8192 + kt0 + vcol);
  *(u16x8*)&sKh[0][srow][scol] = rkh;
  *(u16x8*)&sV [0][vrow][vcol] = rv;
  __syncthreads();

  int cur = 0;
  for (int i = 0; i < ntiles; ++i) {
    int kt = kt0 + i * 32;
    bool more = (i + 1 < ntiles);
    if (more) {                                       // issue next tile's loads early (T14)
      int ktn = kt + 32;
      rkh = *(const u16x8*)(KhB + (size_t)(ktn + srow) * 1024 + scol);
      rv  = *(const u16x8*)(VTB + (size_t)vrow * 8192 + ktn + vcol);
    }

    // wave-uniform: tile contributes nothing for this wave's q-rows
    bool wave_dead = (qb >= P) && (kt + 31 < qb);
    if (!wave_dead) {
      // ---- compute on buf cur ----
      f32x16 s = {};
      __builtin_amdgcn_s_setprio(1);
#pragma unroll
      for (int c = 0; c < 4; ++c) {
        short8 ah = *(const short8*)&sKh[cur][lq][g * 8 + c * 16];
        mfma32(s, ah, bqh[c]);
        mfma32(s, ah, bql[c]);
      }
      __builtin_amdgcn_s_setprio(0);

      // mask: only the diagonal tile (kt == qb, not all-full) needs per-element work
      float p[16];
      if (allfull || kt > qb) {
#pragma unroll
        for (int r = 0; r < 16; ++r) p[r] = s[r];
      } else {
#pragma unroll
        for (int r = 0; r < 16; ++r) {
          int k = kt + (r & 3) + 8 * (r >> 2) + 4 * g;
          p[r] = (qfull || k >= q) ? s[r] : NEG;
        }
      }
      // tree max
      float m01 = fmaxf(p[0], p[1]),  m23 = fmaxf(p[2], p[3]);
      float m45 = fmaxf(p[4], p[5]),  m67 = fmaxf(p[6], p[7]);
      float m89 = fmaxf(p[8], p[9]),  mab = fmaxf(p[10], p[11]);
      float mcd = fmaxf(p[12], p[13]), mef = fmaxf(p[14], p[15]);
      float tmax = fmaxf(fmaxf(fmaxf(m01, m23), fmaxf(m45, m67)),
                         fmaxf(fmaxf(m89, mab), fmaxf(mcd, mef)));
      tmax = fmaxf(tmax, __shfl_xor(tmax, 32));
      // defer-max (T13): rescale only when max grew past THR=8
      if (!__all(tmax - mrun <= 8.0f)) {
        float mnew = fmaxf(mrun, tmax);
        float al = exp2f((mrun - mnew) * L2E);
        lrun *= al; o0 *= al; o1 *= al;
        mrun = mnew;
      }
#pragma unroll
      for (int r = 0; r < 16; ++r)
        p[r] = exp2f((p[r] - mrun) * L2E);            // masked: exp2(~-3e38) == 0
      // tree sum
      float s01 = p[0] + p[1],  s23 = p[2] + p[3],  s45 = p[4] + p[5],  s67 = p[6] + p[7];
      float s89 = p[8] + p[9],  sab = p[10] + p[11], scd = p[12] + p[13], sef = p[14] + p[15];
      float psum = ((s01 + s23) + (s45 + s67)) + ((s89 + sab) + (scd + sef));
      psum += __shfl_xor(psum, 32);
      lrun += psum;

      // P -> LDS transpose via cvt_pk (pairs of adjacent k)
#pragma unroll
      for (int tt = 0; tt < 4; ++tt) {
        unsigned int u0, u1;
        asm("v_cvt_pk_bf16_f32 %0, %1, %2" : "=v"(u0) : "v"(p[4 * tt]),     "v"(p[4 * tt + 1]));
        asm("v_cvt_pk_bf16_f32 %0, %1, %2" : "=v"(u1) : "v"(p[4 * tt + 2]), "v"(p[4 * tt + 3]));
        uint2 w; w.x = u0; w.y = u1;
        *(uint2*)&plds[wid][lq][8 * tt + 4 * g] = w;  // k = 8*tt + 4*g + {0..3}
      }
      short8 pb0 = *(const short8*)&plds[wid][lq][g * 8];
      short8 pb1 = *(const short8*)&plds[wid][lq][16 + g * 8];

      // O^T += V^T * P^T (A-frags from staged sV)
      short8 va00 = *(const short8*)&sV[cur][lq][g * 8];
      short8 va01 = *(const short8*)&sV[cur][lq][16 + g * 8];
      short8 va10 = *(const short8*)&sV[cur][32 + lq][g * 8];
      short8 va11 = *(const short8*)&sV[cur][32 + lq][16 + g * 8];
      __builtin_amdgcn_s_setprio(1);
      mfma32(o0, va00, pb0);
      mfma32(o0, va01, pb1);
      mfma32(o1, va10, pb0);
      mfma32(o1, va11, pb1);
      __builtin_amdgcn_s_setprio(0);
    }

    __syncthreads();                                  // all waves done reading buf cur
    if (more) {
      *(u16x8*)&sKh[cur ^ 1][srow][scol] = rkh;       // write-late
      *(u16x8*)&sV [cur ^ 1][vrow][vcol] = rv;
    }
    __syncthreads();                                  // next buf ready
    cur ^= 1;
  }

  // write AO (bf16) in the reference's scrambled layout:
  // AO[b, h*64 + q/16, (q%16)*64 + d]; d = (r&3) + 8*(r>>2) + 4*g -> vectorized per quad
  float inv = 1.0f / lrun;
  size_t obase = (size_t)(b * 1024 + h * 64 + (q >> 4)) * 1024 + (q & 15) * 64;
#pragma unroll
  for (int tt = 0; tt < 4; ++tt) {
    u16x4 w0, w1;
#pragma unroll
    for (int j = 0; j < 4; ++j) {
      w0[j] = f2bf(o0[4 * tt + j] * inv);
      w1[j] = f2bf(o1[4 * tt + j] * inv);
    }
    *(u16x4*)(AOh + obase + 8 * tt + 4 * g)      = w0;
    *(u16x4*)(AOh + obase + 32 + 8 * tt + 4 * g) = w1;
  }
}

// ---------- launch ----------
extern "C" void kernel_launch(void* const* d_in, const int* in_sizes, int n_in,
                              void* d_out, int out_size, void* d_ws, size_t ws_size,
                              hipStream_t stream) {
  (void)in_sizes; (void)n_in; (void)out_size;
  const float* x      = (const float*)d_in[0];
  const int*   prefix = (const int*)d_in[1];
  const float* Wq = (const float*)d_in[2];
  const float* bq = (const float*)d_in[3];
  const float* Wk = (const float*)d_in[4];
  const float* bk = (const float*)d_in[5];
  const float* Wv = (const float*)d_in[6];
  const float* bv = (const float*)d_in[7];
  const float* Wo = (const float*)d_in[8];
  const float* bo = (const float*)d_in[9];
  float* out = (float*)d_out;

  const size_t MBY = 1ull << 20;
  if (ws_size < 144 * MBY) return;
  char* ws = (char*)d_ws;
  unsigned short* xh  = (unsigned short*)(ws + 0 * MBY);
  unsigned short* xl  = (unsigned short*)(ws + 16 * MBY);
  unsigned short* wqh = (unsigned short*)(ws + 32 * MBY);
  unsigned short* wql = (unsigned short*)(ws + 34 * MBY);
  unsigned short* wkh = (unsigned short*)(ws + 36 * MBY);
  unsigned short* wkl = (unsigned short*)(ws + 38 * MBY);
  unsigned short* wvh = (unsigned short*)(ws + 40 * MBY);
  unsigned short* woh = (unsigned short*)(ws + 44 * MBY);
  unsigned short* Qh  = (unsigned short*)(ws + 48 * MBY);
  unsigned short* Ql  = (unsigned short*)(ws + 64 * MBY);
  unsigned short* Kh  = (unsigned short*)(ws + 80 * MBY);
  unsigned short* V   = (unsigned short*)(ws + 112 * MBY);
  unsigned short* VT  = (unsigned short*)(ws + 128 * MBY);
  unsigned short* AOh = V;    // V dead after vtrans

  split_x_kernel<<<1024, 256, 0, stream>>>((const float4*)x, (ushort4*)xh, (ushort4*)xl,
                                           8192 * 1024 / 4);
  wsplit_kernel<<<dim3(32, 32, 4), 256, 0, stream>>>(Wq, Wk, Wv, Wo,
                                                     wqh, wql, wkh, wkl, wvh, woh);
  gemm_kernel<3, 1><<<dim3(8, 64), 256, 0, stream>>>(xh, xl, wqh, wql, bq, Qh, Ql, nullptr,
                                                     8192, 1024, 1024);
  gemm_kernel<3, 0><<<dim3(8, 64), 256, 0, stream>>>(xh, xl, wkh, wkl, bk, Kh, nullptr, nullptr,
                                                     8192, 1024, 1024);
  gemm_kernel<1, 0><<<dim3(8, 64), 256, 0, stream>>>(xh, nullptr, wvh, nullptr, bv, V, nullptr,
                                                     nullptr, 8192, 1024, 1024);
  vtrans_kernel<<<dim3(128, 16), 256, 0, stream>>>(V, VT);
  attn_kernel<<<dim3(128, 8), 256, 0, stream>>>(Qh, Ql, Kh, VT, prefix, AOh);
  gemm_kernel<1, 2><<<dim3(8, 64), 256, 0, stream>>>(AOh, nullptr, woh, nullptr, bo, nullptr,
                                                     nullptr, out, 8192, 1024, 1024);
}